// Round 2
// baseline (2237.862 us; speedup 1.0000x reference)
//
#include <hip/hip_runtime.h>
#include <cmath>

#define BB 2
#define SS 2048
#define DD 2048
#define HH 16
#define HDD 128
#define MTOT (BB*SS)

typedef float f32x4 __attribute__((ext_vector_type(4)));
typedef short s16x8 __attribute__((ext_vector_type(8)));

static constexpr float NEGV = -1e9f;
static constexpr float SM_SCALE = 0.08838834764831845f; // 1/sqrt(128)

// ---------------------------------------------------------------------------
// fp32 -> bf16 hi/lo split helpers (RNE). Error of hi+lo vs fp32 ~2^-18 rel.
// ---------------------------------------------------------------------------
__device__ __forceinline__ unsigned short f32_to_bf16(float x) {
  unsigned int u = __float_as_uint(x);
  u = u + 0x7FFFu + ((u >> 16) & 1u);
  return (unsigned short)(u >> 16);
}
__device__ __forceinline__ float bf16_to_f32(unsigned short h) {
  return __uint_as_float(((unsigned int)h) << 16);
}

__global__ __launch_bounds__(256)
void split_hl(const float* __restrict__ in, unsigned short* __restrict__ hi,
              unsigned short* __restrict__ lo, int n8) {
  int stride = gridDim.x * 256;
  for (int i = blockIdx.x * 256 + threadIdx.x; i < n8; i += stride) {
    const float4* p = (const float4*)in + (size_t)i * 2;
    float4 a = p[0], b = p[1];
    float v[8] = {a.x, a.y, a.z, a.w, b.x, b.y, b.z, b.w};
    s16x8 hv, lv;
#pragma unroll
    for (int j = 0; j < 8; ++j) {
      unsigned short h = f32_to_bf16(v[j]);
      hv[j] = (short)h;
      lv[j] = (short)f32_to_bf16(v[j] - bf16_to_f32(h));
    }
    *(s16x8*)(hi + (size_t)i * 8) = hv;
    *(s16x8*)(lo + (size_t)i * 8) = lv;
  }
}

// ---------------------------------------------------------------------------
// C[M,N] = (Ah+Al)[M,K] * ((Bh+Bl)[N,K])^T via 3-term bf16 MFMA split.
// 128x128 tile, BK=32, 256 threads (4 waves, 2x2 wave grid, 64x64/wave).
// LDS: 32 subtiles of 1KiB, each a 16(row)x32(k) bf16 fragment tile stored
// in MFMA fragment-lane order: global source is pre-swizzled per-lane
// (row = l&15, k-granule = l>>4) so global_load_lds's linear lane*16 dest
// IS fragment order -> ds_read_b128 fragment reads are fully linear
// (zero bank conflicts), m173 pattern.
// ---------------------------------------------------------------------------
__device__ __forceinline__ void async16(void* ldst, const void* gsrc) {
  __builtin_amdgcn_global_load_lds(
      (const __attribute__((address_space(1))) unsigned int*)gsrc,
      (__attribute__((address_space(3))) unsigned int*)ldst, 16, 0, 0);
}

__global__ __launch_bounds__(256)
void gemm_split(const unsigned short* __restrict__ Ah, const unsigned short* __restrict__ Al,
                const unsigned short* __restrict__ Bh, const unsigned short* __restrict__ Bl,
                float* __restrict__ C, int M, int N, int K) {
  __shared__ unsigned short lds[32 * 512];   // 32 KiB: [mat 0..3][subtile 0..7][512]
  const int tid = threadIdx.x;
  const int l   = tid & 63;
  const int w   = tid >> 6;        // wave 0..3; wave w stages matrix w
  const int m0  = blockIdx.y * 128;
  const int n0  = blockIdx.x * 128;
  const int wm  = w >> 1, wn = w & 1;

  const unsigned short* mp = (w == 0) ? Ah : (w == 1) ? Al : (w == 2) ? Bh : Bl;
  const int rb = (w < 2) ? m0 : n0;
  // pre-swizzled per-lane source: (row rb + s*16 + (l&15), k-granule l>>4)
  const unsigned short* gs = mp + (size_t)(rb + (l & 15)) * K + ((l >> 4) * 8);
  unsigned short* ldw = &lds[(w * 8) * 512];

  f32x4 acc[4][4];
#pragma unroll
  for (int i = 0; i < 4; ++i)
#pragma unroll
    for (int j = 0; j < 4; ++j) {
      f32x4 z = {0.f, 0.f, 0.f, 0.f};
      acc[i][j] = z;
    }

  for (int k0 = 0; k0 < K; k0 += 32) {
    __syncthreads();                       // prior iter's ds_reads done
#pragma unroll
    for (int s = 0; s < 8; ++s)
      async16(ldw + s * 512, gs + (size_t)s * 16 * K + k0);
    __syncthreads();                       // drains vmcnt -> LDS ready

    s16x8 ah[4], al[4], bh[4], bl[4];
#pragma unroll
    for (int i = 0; i < 4; ++i) {
      ah[i] = *(const s16x8*)&lds[(0 * 8 + wm * 4 + i) * 512 + l * 8];
      al[i] = *(const s16x8*)&lds[(1 * 8 + wm * 4 + i) * 512 + l * 8];
      bh[i] = *(const s16x8*)&lds[(2 * 8 + wn * 4 + i) * 512 + l * 8];
      bl[i] = *(const s16x8*)&lds[(3 * 8 + wn * 4 + i) * 512 + l * 8];
    }
#pragma unroll
    for (int i = 0; i < 4; ++i)
#pragma unroll
      for (int j = 0; j < 4; ++j) {
        acc[i][j] = __builtin_amdgcn_mfma_f32_16x16x32_bf16(ah[i], bh[j], acc[i][j], 0, 0, 0);
        acc[i][j] = __builtin_amdgcn_mfma_f32_16x16x32_bf16(ah[i], bl[j], acc[i][j], 0, 0, 0);
        acc[i][j] = __builtin_amdgcn_mfma_f32_16x16x32_bf16(al[i], bh[j], acc[i][j], 0, 0, 0);
      }
  }

  // epilogue: C/D layout col = l&15, row = (l>>4)*4 + r  [m89-verified]
  const int r4 = (l >> 4) * 4, cn = l & 15;
#pragma unroll
  for (int i = 0; i < 4; ++i)
#pragma unroll
    for (int j = 0; j < 4; ++j) {
      float* Cp = C + (size_t)(m0 + wm * 64 + i * 16 + r4) * N + (n0 + wn * 64 + j * 16 + cn);
#pragma unroll
      for (int r = 0; r < 4; ++r) Cp[(size_t)r * N] = acc[i][j][r];
    }
}

// ---------------------------------------------------------------------------
// Fallback fp32 GEMM (round-0 baseline) — used only if ws_size is too small
// for the split buffers.
// ---------------------------------------------------------------------------
__global__ __launch_bounds__(256)
void gemm_nt_f32(const float* __restrict__ A, const float* __restrict__ W,
                 float* __restrict__ C, int M, int N, int K) {
  __shared__ float As[16][128];
  __shared__ float Bs[16][128];
  const int tid = threadIdx.x;
  const int tx = tid & 15, ty = tid >> 4;
  const int m0 = blockIdx.y * 128, n0 = blockIdx.x * 128;
  const int lrow = tid >> 2, lk = (tid & 3) << 2;
  const float* Ap  = A + (size_t)(m0 + lrow) * K + lk;
  const float* Ap2 = Ap + (size_t)64 * K;
  const float* Wp  = W + (size_t)(n0 + lrow) * K + lk;
  const float* Wp2 = Wp + (size_t)64 * K;
  float acc[8][8];
#pragma unroll
  for (int i = 0; i < 8; ++i)
#pragma unroll
    for (int j = 0; j < 8; ++j) acc[i][j] = 0.0f;
  for (int k0 = 0; k0 < K; k0 += 16) {
    float4 a0 = *(const float4*)(Ap + k0);
    float4 a1 = *(const float4*)(Ap2 + k0);
    float4 b0 = *(const float4*)(Wp + k0);
    float4 b1 = *(const float4*)(Wp2 + k0);
    __syncthreads();
    As[lk+0][lrow] = a0.x; As[lk+1][lrow] = a0.y; As[lk+2][lrow] = a0.z; As[lk+3][lrow] = a0.w;
    As[lk+0][64+lrow] = a1.x; As[lk+1][64+lrow] = a1.y; As[lk+2][64+lrow] = a1.z; As[lk+3][64+lrow] = a1.w;
    Bs[lk+0][lrow] = b0.x; Bs[lk+1][lrow] = b0.y; Bs[lk+2][lrow] = b0.z; Bs[lk+3][lrow] = b0.w;
    Bs[lk+0][64+lrow] = b1.x; Bs[lk+1][64+lrow] = b1.y; Bs[lk+2][64+lrow] = b1.z; Bs[lk+3][64+lrow] = b1.w;
    __syncthreads();
#pragma unroll
    for (int kk = 0; kk < 16; ++kk) {
      float a[8], b[8];
      *(float4*)(a)   = *(const float4*)&As[kk][ty*8];
      *(float4*)(a+4) = *(const float4*)&As[kk][ty*8+4];
      *(float4*)(b)   = *(const float4*)&Bs[kk][tx*8];
      *(float4*)(b+4) = *(const float4*)&Bs[kk][tx*8+4];
#pragma unroll
      for (int i = 0; i < 8; ++i)
#pragma unroll
        for (int j = 0; j < 8; ++j) acc[i][j] = fmaf(a[i], b[j], acc[i][j]);
    }
  }
#pragma unroll
  for (int i = 0; i < 8; ++i) {
    float* Cp = C + (size_t)(m0 + ty*8 + i) * N + n0 + tx*8;
    *(float4*)(Cp)   = make_float4(acc[i][0], acc[i][1], acc[i][2], acc[i][3]);
    *(float4*)(Cp+4) = make_float4(acc[i][4], acc[i][5], acc[i][6], acc[i][7]);
  }
}

// ---------------------------------------------------------------------------
// In-place RoPE on Q and K (interleaved-pair convention).
// ---------------------------------------------------------------------------
__global__ __launch_bounds__(256)
void rope_qk(float* __restrict__ Qb, float* __restrict__ Kb,
             const float* __restrict__ Fc, const float* __restrict__ Fs) {
  int idx = blockIdx.x * 256 + threadIdx.x;
  int m   = idx >> 10;
  int rem = idx & 1023;
  int h   = rem >> 6;
  int i   = rem & 63;
  int s   = m & (SS - 1);
  float c  = Fc[s*64 + i];
  float sn = Fs[s*64 + i];
  size_t base = (size_t)m * DD + h*HDD + 2*i;
  float2 q = *(float2*)(Qb + base);
  float2 k = *(float2*)(Kb + base);
  *(float2*)(Qb + base) = make_float2(q.x*c - q.y*sn, q.x*sn + q.y*c);
  *(float2*)(Kb + base) = make_float2(k.x*c - k.y*sn, k.x*sn + k.y*c);
}

// ---------------------------------------------------------------------------
// Flash-style causal attention, fp32 (unchanged round-0 logic).
// ---------------------------------------------------------------------------
__global__ __launch_bounds__(256)
void attn_f32(const float* __restrict__ Q, const float* __restrict__ K,
              const float* __restrict__ V, float* __restrict__ O) {
  __shared__ float Qs[32][132];
  __shared__ float Ks[32][132];
  __shared__ float Vs[32][132];
  __shared__ float Ss[32][40];
  __shared__ float m_row[32], l_row[32], scale_row[32];

  const int tid = threadIdx.x;
  const int qt = blockIdx.x, h = blockIdx.y, b = blockIdx.z;
  const int q0 = qt * 32;

  const float* Qbase = Q + (size_t)b*SS*DD + h*HDD;
  const float* Kbase = K + (size_t)b*SS*DD + h*HDD;
  const float* Vbase = V + (size_t)b*SS*DD + h*HDD;

#pragma unroll
  for (int it = 0; it < 4; ++it) {
    int idx = it*256 + tid;
    int rr = idx >> 5, c4 = (idx & 31) << 2;
    *(float4*)&Qs[rr][c4] = *(const float4*)(Qbase + (size_t)(q0 + rr)*DD + c4);
  }
  if (tid < 32) { m_row[tid] = -INFINITY; l_row[tid] = 0.0f; }

  float acc[16];
#pragma unroll
  for (int i = 0; i < 16; ++i) acc[i] = 0.0f;

  const int r = tid >> 3, j = tid & 7;
  const int qi = q0 + r;
  const int nkt = qt + 1;

  for (int kt = 0; kt < nkt; ++kt) {
    const int kb = kt * 32;
    __syncthreads();
#pragma unroll
    for (int it = 0; it < 4; ++it) {
      int idx = it*256 + tid;
      int rr = idx >> 5, c4 = (idx & 31) << 2;
      *(float4*)&Ks[rr][c4] = *(const float4*)(Kbase + (size_t)(kb + rr)*DD + c4);
      *(float4*)&Vs[rr][c4] = *(const float4*)(Vbase + (size_t)(kb + rr)*DD + c4);
    }
    __syncthreads();

    float sc[4] = {0.f, 0.f, 0.f, 0.f};
    for (int k4 = 0; k4 < 32; ++k4) {
      float4 qv = *(const float4*)&Qs[r][k4*4];
#pragma unroll
      for (int cc = 0; cc < 4; ++cc) {
        float4 kv = *(const float4*)&Ks[cc*8 + j][k4*4];
        sc[cc] = fmaf(qv.x, kv.x, sc[cc]);
        sc[cc] = fmaf(qv.y, kv.y, sc[cc]);
        sc[cc] = fmaf(qv.z, kv.z, sc[cc]);
        sc[cc] = fmaf(qv.w, kv.w, sc[cc]);
      }
    }
    float tmax = -INFINITY;
#pragma unroll
    for (int cc = 0; cc < 4; ++cc) {
      int kj = kb + cc*8 + j;
      sc[cc] = (kj <= qi) ? sc[cc]*SM_SCALE : NEGV;
      tmax = fmaxf(tmax, sc[cc]);
    }
    tmax = fmaxf(tmax, __shfl_xor(tmax, 1, 8));
    tmax = fmaxf(tmax, __shfl_xor(tmax, 2, 8));
    tmax = fmaxf(tmax, __shfl_xor(tmax, 4, 8));
    float m_old = m_row[r];
    float m_new = fmaxf(m_old, tmax);
    float psum = 0.0f;
#pragma unroll
    for (int cc = 0; cc < 4; ++cc) {
      float p = __expf(sc[cc] - m_new);
      Ss[r][cc*8 + j] = p;
      psum += p;
    }
    psum += __shfl_xor(psum, 1, 8);
    psum += __shfl_xor(psum, 2, 8);
    psum += __shfl_xor(psum, 4, 8);
    if (j == 0) {
      m_row[r] = m_new;
      float scl = __expf(m_old - m_new);
      scale_row[r] = scl;
      l_row[r] = l_row[r]*scl + psum;
    }
    __syncthreads();

    const float scl = scale_row[r];
#pragma unroll
    for (int i = 0; i < 16; ++i) acc[i] *= scl;
    for (int c = 0; c < 32; ++c) {
      float p = Ss[r][c];
      const float* vrow = &Vs[c][j*16];
      float vv[16];
      *(float4*)(vv)    = *(const float4*)(vrow);
      *(float4*)(vv+4)  = *(const float4*)(vrow+4);
      *(float4*)(vv+8)  = *(const float4*)(vrow+8);
      *(float4*)(vv+12) = *(const float4*)(vrow+12);
#pragma unroll
      for (int i = 0; i < 16; ++i) acc[i] = fmaf(p, vv[i], acc[i]);
    }
  }

  const float rl = 1.0f / l_row[r];
  float* Op = O + (size_t)(b*SS + q0 + r)*DD + h*HDD + j*16;
#pragma unroll
  for (int v4 = 0; v4 < 4; ++v4) {
    *(float4*)(Op + v4*4) = make_float4(acc[v4*4+0]*rl, acc[v4*4+1]*rl,
                                        acc[v4*4+2]*rl, acc[v4*4+3]*rl);
  }
}

// ---------------------------------------------------------------------------
extern "C" void kernel_launch(void* const* d_in, const int* in_sizes, int n_in,
                              void* d_out, int out_size, void* d_ws, size_t ws_size,
                              hipStream_t stream) {
  (void)in_sizes; (void)n_in; (void)out_size;
  const float* x  = (const float*)d_in[0];
  const float* wq = (const float*)d_in[1];
  const float* wk = (const float*)d_in[2];
  const float* wv = (const float*)d_in[3];
  const float* wo = (const float*)d_in[4];
  const float* fc = (const float*)d_in[5];
  const float* fs = (const float*)d_in[6];
  float* out = (float*)d_out;

  const size_t elems  = (size_t)MTOT * DD;   // 8.39M
  const size_t welems = (size_t)DD * DD;     // 4.19M

  float* qb = (float*)d_ws;
  float* kb = qb + elems;
  float* vb = kb + elems;

  dim3 blk(256);
  dim3 gg(DD/128, MTOT/128);   // (16, 32)

  // split-path buffers after qb/kb/vb
  const size_t need = elems*4*3 + elems*2*2 + welems*2*8;  // ~201.3 MB

  if (ws_size >= need) {
    unsigned short* xh = (unsigned short*)(vb + elems);
    unsigned short* xl = xh + elems;
    unsigned short* wsp = xl + elems;
    unsigned short* wqh = wsp;              unsigned short* wql = wqh + welems;
    unsigned short* wkh = wql + welems;     unsigned short* wkl = wkh + welems;
    unsigned short* wvh = wkl + welems;     unsigned short* wvl = wvh + welems;
    unsigned short* woh = wvl + welems;     unsigned short* wol = woh + welems;

    split_hl<<<dim3(2048), blk, 0, stream>>>(x,  xh,  xl,  (int)(elems/8));
    split_hl<<<dim3(2048), blk, 0, stream>>>(wq, wqh, wql, (int)(welems/8));
    split_hl<<<dim3(2048), blk, 0, stream>>>(wk, wkh, wkl, (int)(welems/8));
    split_hl<<<dim3(2048), blk, 0, stream>>>(wv, wvh, wvl, (int)(welems/8));
    split_hl<<<dim3(2048), blk, 0, stream>>>(wo, woh, wol, (int)(welems/8));

    gemm_split<<<gg, blk, 0, stream>>>(xh, xl, wqh, wql, qb, MTOT, DD, DD);
    gemm_split<<<gg, blk, 0, stream>>>(xh, xl, wkh, wkl, kb, MTOT, DD, DD);
    gemm_split<<<gg, blk, 0, stream>>>(xh, xl, wvh, wvl, vb, MTOT, DD, DD);
    rope_qk<<<dim3((MTOT*HH*64)/256), blk, 0, stream>>>(qb, kb, fc, fs);
    attn_f32<<<dim3(SS/32, HH, BB), blk, 0, stream>>>(qb, kb, vb, qb);
    // split attention output (in qb) reusing xh/xl, then O-projection
    split_hl<<<dim3(2048), blk, 0, stream>>>(qb, xh, xl, (int)(elems/8));
    gemm_split<<<gg, blk, 0, stream>>>(xh, xl, woh, wol, out, MTOT, DD, DD);
  } else {
    gemm_nt_f32<<<gg, blk, 0, stream>>>(x, wq, qb, MTOT, DD, DD);
    gemm_nt_f32<<<gg, blk, 0, stream>>>(x, wk, kb, MTOT, DD, DD);
    gemm_nt_f32<<<gg, blk, 0, stream>>>(x, wv, vb, MTOT, DD, DD);
    rope_qk<<<dim3((MTOT*HH*64)/256), blk, 0, stream>>>(qb, kb, fc, fs);
    attn_f32<<<dim3(SS/32, HH, BB), blk, 0, stream>>>(qb, kb, vb, qb);
    gemm_nt_f32<<<gg, blk, 0, stream>>>(qb, wo, out, MTOT, DD, DD);
  }
}

// Round 6
// 978.632 us; speedup vs baseline: 2.2867x; 2.2867x over previous
//
#include <hip/hip_runtime.h>
#include <cmath>

#define BB 2
#define SS 2048
#define DD 2048
#define HH 16
#define HDD 128
#define MTOT (BB*SS)

typedef float f32x4 __attribute__((ext_vector_type(4)));
typedef short s16x8 __attribute__((ext_vector_type(8)));
typedef short s16x4v __attribute__((ext_vector_type(4)));

static constexpr float NEGV = -1e9f;
static constexpr float SM_SCALE = 0.08838834764831845f; // 1/sqrt(128)

// ---------------------------------------------------------------------------
// fp32 -> bf16 hi/lo split helpers (RNE). hi+lo ~ 2^-18 relative error.
// ---------------------------------------------------------------------------
__device__ __forceinline__ unsigned short f32_to_bf16(float x) {
  unsigned int u = __float_as_uint(x);
  u = u + 0x7FFFu + ((u >> 16) & 1u);
  return (unsigned short)(u >> 16);
}
__device__ __forceinline__ float bf16_to_f32(unsigned short h) {
  return __uint_as_float(((unsigned int)h) << 16);
}

__global__ __launch_bounds__(256)
void split_hl(const float* __restrict__ in, unsigned short* __restrict__ hi,
              unsigned short* __restrict__ lo, int n8) {
  int stride = gridDim.x * 256;
  for (int i = blockIdx.x * 256 + threadIdx.x; i < n8; i += stride) {
    const float4* p = (const float4*)in + (size_t)i * 2;
    float4 a = p[0], b = p[1];
    float v[8] = {a.x, a.y, a.z, a.w, b.x, b.y, b.z, b.w};
    s16x8 hv, lv;
#pragma unroll
    for (int j = 0; j < 8; ++j) {
      unsigned short h = f32_to_bf16(v[j]);
      hv[j] = (short)h;
      lv[j] = (short)f32_to_bf16(v[j] - bf16_to_f32(h));
    }
    *(s16x8*)(hi + (size_t)i * 8) = hv;
    *(s16x8*)(lo + (size_t)i * 8) = lv;
  }
}

// ---------------------------------------------------------------------------
__device__ __forceinline__ void async16(void* ldst, const void* gsrc) {
  __builtin_amdgcn_global_load_lds(
      (const __attribute__((address_space(1))) unsigned int*)gsrc,
      (__attribute__((address_space(3))) unsigned int*)ldst, 16, 0, 0);
}

// ---------------------------------------------------------------------------
// GEMM core: C = (Ah+Al)[M,K] * ((Bh+Bl)[N,K])^T, 3-term bf16 MFMA split.
// 128x128 tile, BK=32, 4 waves. Three epilogues: fp32 C / bf16 hi-lo C /
// bf16 hi-lo C^T (for the V projection, so attention can stage V^T like K).
// ---------------------------------------------------------------------------
#define GEMM_BODY                                                              \
  __shared__ unsigned short lds[32 * 512];                                     \
  const int tid = threadIdx.x;                                                 \
  const int l   = tid & 63;                                                    \
  const int w   = tid >> 6;                                                    \
  const int m0  = blockIdx.y * 128;                                            \
  const int n0  = blockIdx.x * 128;                                            \
  const int wm  = w >> 1, wn = w & 1;                                          \
  const unsigned short* mp = (w == 0) ? Ah : (w == 1) ? Al : (w == 2) ? Bh : Bl;\
  const int rb = (w < 2) ? m0 : n0;                                            \
  const unsigned short* gs = mp + (size_t)(rb + (l & 15)) * K + ((l >> 4) * 8);\
  unsigned short* ldw = &lds[(w * 8) * 512];                                   \
  f32x4 acc[4][4];                                                             \
  _Pragma("unroll") for (int i = 0; i < 4; ++i)                                \
  _Pragma("unroll") for (int j = 0; j < 4; ++j) {                              \
    f32x4 z = {0.f, 0.f, 0.f, 0.f}; acc[i][j] = z; }                           \
  for (int k0 = 0; k0 < K; k0 += 32) {                                         \
    __syncthreads();                                                           \
    _Pragma("unroll") for (int s = 0; s < 8; ++s)                              \
      async16(ldw + s * 512, gs + (size_t)s * 16 * K + k0);                    \
    __syncthreads();                                                           \
    s16x8 ah[4], al[4], bh[4], bl[4];                                          \
    _Pragma("unroll") for (int i = 0; i < 4; ++i) {                            \
      ah[i] = *(const s16x8*)&lds[(0 * 8 + wm * 4 + i) * 512 + l * 8];         \
      al[i] = *(const s16x8*)&lds[(1 * 8 + wm * 4 + i) * 512 + l * 8];         \
      bh[i] = *(const s16x8*)&lds[(2 * 8 + wn * 4 + i) * 512 + l * 8];         \
      bl[i] = *(const s16x8*)&lds[(3 * 8 + wn * 4 + i) * 512 + l * 8];         \
    }                                                                          \
    _Pragma("unroll") for (int i = 0; i < 4; ++i)                              \
    _Pragma("unroll") for (int j = 0; j < 4; ++j) {                            \
      acc[i][j] = __builtin_amdgcn_mfma_f32_16x16x32_bf16(ah[i], bh[j], acc[i][j], 0, 0, 0); \
      acc[i][j] = __builtin_amdgcn_mfma_f32_16x16x32_bf16(ah[i], bl[j], acc[i][j], 0, 0, 0); \
      acc[i][j] = __builtin_amdgcn_mfma_f32_16x16x32_bf16(al[i], bh[j], acc[i][j], 0, 0, 0); \
    }                                                                          \
  }                                                                            \
  const int r4 = (l >> 4) * 4, cn = l & 15;

__global__ __launch_bounds__(256)
void gemm_split(const unsigned short* __restrict__ Ah, const unsigned short* __restrict__ Al,
                const unsigned short* __restrict__ Bh, const unsigned short* __restrict__ Bl,
                float* __restrict__ C, int M, int N, int K) {
  GEMM_BODY
#pragma unroll
  for (int i = 0; i < 4; ++i)
#pragma unroll
    for (int j = 0; j < 4; ++j) {
      float* Cp = C + (size_t)(m0 + wm * 64 + i * 16 + r4) * N + (n0 + wn * 64 + j * 16 + cn);
#pragma unroll
      for (int r = 0; r < 4; ++r) Cp[(size_t)r * N] = acc[i][j][r];
    }
}

__global__ __launch_bounds__(256)
void gemm_splitB(const unsigned short* __restrict__ Ah, const unsigned short* __restrict__ Al,
                 const unsigned short* __restrict__ Bh, const unsigned short* __restrict__ Bl,
                 unsigned short* __restrict__ Ch, unsigned short* __restrict__ Cl,
                 int M, int N, int K) {
  GEMM_BODY
#pragma unroll
  for (int i = 0; i < 4; ++i)
#pragma unroll
    for (int j = 0; j < 4; ++j) {
      size_t idx = (size_t)(m0 + wm * 64 + i * 16 + r4) * N + (n0 + wn * 64 + j * 16 + cn);
#pragma unroll
      for (int r = 0; r < 4; ++r) {
        float v = acc[i][j][r];
        unsigned short h = f32_to_bf16(v);
        Ch[idx + (size_t)r * N] = h;
        Cl[idx + (size_t)r * N] = f32_to_bf16(v - bf16_to_f32(h));
      }
    }
}

// transposed epilogue: Ch/Cl are [N][M]
__global__ __launch_bounds__(256)
void gemm_splitBT(const unsigned short* __restrict__ Ah, const unsigned short* __restrict__ Al,
                  const unsigned short* __restrict__ Bh, const unsigned short* __restrict__ Bl,
                  unsigned short* __restrict__ Ch, unsigned short* __restrict__ Cl,
                  int M, int N, int K) {
  GEMM_BODY
#pragma unroll
  for (int i = 0; i < 4; ++i)
#pragma unroll
    for (int j = 0; j < 4; ++j) {
      size_t idxT = (size_t)(n0 + wn * 64 + j * 16 + cn) * M + (m0 + wm * 64 + i * 16 + r4);
      s16x4v hv, lv;
#pragma unroll
      for (int r = 0; r < 4; ++r) {
        float v = acc[i][j][r];
        unsigned short h2 = f32_to_bf16(v);
        hv[r] = (short)h2;
        lv[r] = (short)f32_to_bf16(v - bf16_to_f32(h2));
      }
      *(s16x4v*)&Ch[idxT] = hv;
      *(s16x4v*)&Cl[idxT] = lv;
    }
}

// ---------------------------------------------------------------------------
// RoPE on bf16 hi/lo Q and K (interleaved-pair). 8 elems (4 pairs)/thread.
// ---------------------------------------------------------------------------
__global__ __launch_bounds__(256)
void rope_hl(unsigned short* __restrict__ Qh, unsigned short* __restrict__ Ql,
             unsigned short* __restrict__ Kh, unsigned short* __restrict__ Kl,
             const float* __restrict__ Fc, const float* __restrict__ Fs) {
  int idx = blockIdx.x * 256 + threadIdx.x;   // < MTOT*16*16
  int m   = idx >> 8;
  int rem = idx & 255;
  int h   = rem >> 4;
  int i4  = rem & 15;
  int s   = m & (SS - 1);
  size_t base = (size_t)m * DD + h * HDD + i4 * 8;
  float4 c  = *(const float4*)&Fc[s * 64 + i4 * 4];
  float4 sn = *(const float4*)&Fs[s * 64 + i4 * 4];
  float cc[4] = {c.x, c.y, c.z, c.w}, ss[4] = {sn.x, sn.y, sn.z, sn.w};
#pragma unroll
  for (int mtx = 0; mtx < 2; ++mtx) {
    unsigned short* Hb = mtx ? Kh : Qh;
    unsigned short* Lb = mtx ? Kl : Ql;
    s16x8 vh = *(s16x8*)&Hb[base];
    s16x8 vl = *(s16x8*)&Lb[base];
    float q[8];
#pragma unroll
    for (int e = 0; e < 8; ++e)
      q[e] = bf16_to_f32((unsigned short)vh[e]) + bf16_to_f32((unsigned short)vl[e]);
    s16x8 oh, ol;
#pragma unroll
    for (int p = 0; p < 4; ++p) {
      float re = q[2*p], im = q[2*p+1];
      float nr = re * cc[p] - im * ss[p];
      float ni = re * ss[p] + im * cc[p];
      unsigned short hr = f32_to_bf16(nr);
      unsigned short hi = f32_to_bf16(ni);
      oh[2*p] = (short)hr;   ol[2*p]   = (short)f32_to_bf16(nr - bf16_to_f32(hr));
      oh[2*p+1] = (short)hi; ol[2*p+1] = (short)f32_to_bf16(ni - bf16_to_f32(hi));
    }
    *(s16x8*)&Hb[base] = oh;
    *(s16x8*)&Lb[base] = ol;
  }
}

// ---------------------------------------------------------------------------
// Flash attention, bf16 hi/lo MFMA, fp32-grade accuracy. CANONICAL layouts
// only: V is consumed pre-transposed (VT[n=dglob][m=token], produced by
// gemm_splitBT) and staged exactly like K/B in the verified GEMM. P is packed
// in canonical A-slot order (k = 8g+e). No tr_read, no permutations.
// Block = (q-tile 64, h, b); 4 waves x 16 q-rows; K-tile 64. LDS 80 KiB.
// ---------------------------------------------------------------------------
#define KH0  0
#define KL0  8192
#define VTH0 16384
#define VTL0 24576
#define P0   32768

__global__ __launch_bounds__(256)
void attn_mfma(const unsigned short* __restrict__ Qh, const unsigned short* __restrict__ Ql,
               const unsigned short* __restrict__ Kh, const unsigned short* __restrict__ Kl,
               const unsigned short* __restrict__ VTh, const unsigned short* __restrict__ VTl,
               unsigned short* __restrict__ Oh, unsigned short* __restrict__ Ol) {
  __shared__ unsigned short lds[40960];  // 80 KiB
  const int tid = threadIdx.x, l = tid & 63, w = tid >> 6;
  const int qt = blockIdx.x, h = blockIdx.y, b = blockIdx.z;
  const int q0 = qt * 64;
  const int qrow = q0 + w * 16 + ((l >> 4) << 2);

  // ---- Q fragments (registers): lane&15 = q-row, slots (l>>4)*8+e, t = 32-d window
  const size_t rowQ = (size_t)(b * SS + q0 + w * 16 + (l & 15)) * DD + h * HDD + ((l >> 4) * 8);
  s16x8 qh[4], ql[4];
#pragma unroll
  for (int t = 0; t < 4; ++t) {
    qh[t] = *(const s16x8*)&Qh[rowQ + t * 32];
    ql[t] = *(const s16x8*)&Ql[rowQ + t * 32];
  }

  // ---- staging source (wave w stages matrix w) ----
  const unsigned short* sbase = (w == 0) ? Kh : (w == 1) ? Kl : (w == 2) ? VTh : VTl;
  size_t gsl;
  int dst0;
  if (w < 2) {   // K: rows = k-token (l&15), cols = d
    gsl  = (size_t)(b * SS + (l & 15)) * DD + h * HDD + ((l >> 4) * 8);
    dst0 = (w == 0) ? KH0 : KL0;
  } else {       // VT: rows = dglob (l&15), cols = token
    gsl  = (size_t)(h * HDD + (l & 15)) * MTOT + b * SS + ((l >> 4) * 8);
    dst0 = (w == 2) ? VTH0 : VTL0;
  }

  f32x4 acc[8];
#pragma unroll
  for (int f = 0; f < 8; ++f) { f32x4 z = {0.f,0.f,0.f,0.f}; acc[f] = z; }
  float m_prev[4], l_run[4];
#pragma unroll
  for (int r = 0; r < 4; ++r) { m_prev[r] = -INFINITY; l_run[r] = 0.f; }

  const int nkt = qt + 1;

  for (int kt_t = 0; kt_t < nkt; ++kt_t) {
    const int kb = kt_t * 64;
    __syncthreads();
    if (w < 2) {
#pragma unroll
      for (int sb = 0; sb < 4; ++sb)
#pragma unroll
        for (int t = 0; t < 4; ++t)
          async16(&lds[dst0 + (sb * 4 + t) * 512],
                  sbase + gsl + (size_t)(kb + sb * 16) * DD + t * 32);
    } else {
#pragma unroll
      for (int dt = 0; dt < 8; ++dt)
#pragma unroll
        for (int t = 0; t < 2; ++t)
          async16(&lds[dst0 + (dt * 2 + t) * 512],
                  sbase + gsl + (size_t)(dt * 16) * MTOT + kb + t * 32);
    }
    __syncthreads();

    // ---- QK^T (3-term split): S[q][kcol], 4 col-subtiles sb ----
    float sc[4][4];
    __builtin_amdgcn_s_setprio(1);
#pragma unroll
    for (int sb = 0; sb < 4; ++sb) {
      f32x4 s = {0.f, 0.f, 0.f, 0.f};
#pragma unroll
      for (int t = 0; t < 4; ++t) {
        s16x8 kbh = *(const s16x8*)&lds[KH0 + (sb * 4 + t) * 512 + l * 8];
        s16x8 kbl = *(const s16x8*)&lds[KL0 + (sb * 4 + t) * 512 + l * 8];
        s = __builtin_amdgcn_mfma_f32_16x16x32_bf16(qh[t], kbh, s, 0, 0, 0);
        s = __builtin_amdgcn_mfma_f32_16x16x32_bf16(qh[t], kbl, s, 0, 0, 0);
        s = __builtin_amdgcn_mfma_f32_16x16x32_bf16(ql[t], kbh, s, 0, 0, 0);
      }
      int kcol = kb + sb * 16 + (l & 15);
#pragma unroll
      for (int r = 0; r < 4; ++r)
        sc[sb][r] = (kcol <= qrow + r) ? s[r] * SM_SCALE : NEGV;
    }
    __builtin_amdgcn_s_setprio(0);

    // ---- online softmax (per lane: 4 q-rows; reduce over 16 lanes) ----
    float p[4][4];
#pragma unroll
    for (int r = 0; r < 4; ++r) {
      float tm = fmaxf(fmaxf(sc[0][r], sc[1][r]), fmaxf(sc[2][r], sc[3][r]));
      tm = fmaxf(tm, __shfl_xor(tm, 1));
      tm = fmaxf(tm, __shfl_xor(tm, 2));
      tm = fmaxf(tm, __shfl_xor(tm, 4));
      tm = fmaxf(tm, __shfl_xor(tm, 8));
      float mn = fmaxf(m_prev[r], tm);
      float ps = 0.f;
#pragma unroll
      for (int sb = 0; sb < 4; ++sb) { p[sb][r] = __expf(sc[sb][r] - mn); ps += p[sb][r]; }
      ps += __shfl_xor(ps, 1); ps += __shfl_xor(ps, 2);
      ps += __shfl_xor(ps, 4); ps += __shfl_xor(ps, 8);
      float scl = __expf(m_prev[r] - mn);
      l_run[r] = l_run[r] * scl + ps;
      m_prev[r] = mn;
#pragma unroll
      for (int f = 0; f < 8; ++f) acc[f][r] *= scl;
    }

    // ---- pack P (hi/lo) into canonical A-fragment LDS:
    //      element [ks*512 + lane*8 + e] = P[lane&15][32ks + 8*(lane>>4) + e]
#pragma unroll
    for (int sb = 0; sb < 4; ++sb)
#pragma unroll
      for (int r = 0; r < 4; ++r) {
        float pv = p[sb][r];
        unsigned short ph = f32_to_bf16(pv);
        unsigned short pl2 = f32_to_bf16(pv - bf16_to_f32(ph));
        int q   = ((l >> 4) << 2) + r;          // this value's q-row
        int k32 = ((sb & 1) << 4) + (l & 15);   // k within 32-window
        int off = ((sb >> 1) << 9) + ((q + ((k32 >> 3) << 4)) << 3) + (k32 & 7);
        lds[P0 + w * 2048 + off] = ph;
        lds[P0 + w * 2048 + 1024 + off] = pl2;
      }

    // ---- PV (3-term split): canonical A (P) x canonical B (VT) ----
    s16x8 pah[2], pal[2];
#pragma unroll
    for (int ks = 0; ks < 2; ++ks) {
      pah[ks] = *(const s16x8*)&lds[P0 + w * 2048 + ks * 512 + l * 8];
      pal[ks] = *(const s16x8*)&lds[P0 + w * 2048 + 1024 + ks * 512 + l * 8];
    }
    __builtin_amdgcn_s_setprio(1);
#pragma unroll
    for (int dt = 0; dt < 8; ++dt) {
#pragma unroll
      for (int ks = 0; ks < 2; ++ks) {
        s16x8 vbh = *(const s16x8*)&lds[VTH0 + (dt * 2 + ks) * 512 + l * 8];
        s16x8 vbl = *(const s16x8*)&lds[VTL0 + (dt * 2 + ks) * 512 + l * 8];
        acc[dt] = __builtin_amdgcn_mfma_f32_16x16x32_bf16(pah[ks], vbh, acc[dt], 0, 0, 0);
        acc[dt] = __builtin_amdgcn_mfma_f32_16x16x32_bf16(pah[ks], vbl, acc[dt], 0, 0, 0);
        acc[dt] = __builtin_amdgcn_mfma_f32_16x16x32_bf16(pal[ks], vbh, acc[dt], 0, 0, 0);
      }
    }
    __builtin_amdgcn_s_setprio(0);
  }

  // ---- epilogue: O = acc / l_run, split to bf16 hi/lo ----
  float rl[4];
#pragma unroll
  for (int r = 0; r < 4; ++r) rl[r] = 1.f / l_run[r];
  const size_t orow = (size_t)(b * SS + q0 + w * 16 + ((l >> 4) << 2)) * DD + h * HDD + (l & 15);
#pragma unroll
  for (int f = 0; f < 8; ++f)
#pragma unroll
    for (int r = 0; r < 4; ++r) {
      float v = acc[f][r] * rl[r];
      unsigned short vh_ = f32_to_bf16(v);
      Oh[orow + (size_t)r * DD + f * 16] = vh_;
      Ol[orow + (size_t)r * DD + f * 16] = f32_to_bf16(v - bf16_to_f32(vh_));
    }
}

// ---------------------------------------------------------------------------
extern "C" void kernel_launch(void* const* d_in, const int* in_sizes, int n_in,
                              void* d_out, int out_size, void* d_ws, size_t ws_size,
                              hipStream_t stream) {
  (void)in_sizes; (void)n_in; (void)out_size; (void)ws_size;
  const float* x  = (const float*)d_in[0];
  const float* wq = (const float*)d_in[1];
  const float* wk = (const float*)d_in[2];
  const float* wv = (const float*)d_in[3];
  const float* wo = (const float*)d_in[4];
  const float* fc = (const float*)d_in[5];
  const float* fs = (const float*)d_in[6];
  float* out = (float*)d_out;

  const size_t E = (size_t)MTOT * DD;   // 8.39M elems
  const size_t W = (size_t)DD * DD;     // 4.19M elems

  unsigned short* base = (unsigned short*)d_ws;
  unsigned short* Qh = base;
  unsigned short* Ql = Qh + E;
  unsigned short* Kh = Ql + E;
  unsigned short* Kl = Kh + E;
  unsigned short* VTh = Kl + E;         // [DD][MTOT] transposed
  unsigned short* VTl = VTh + E;
  unsigned short* xh = VTl + E;
  unsigned short* xl = xh + E;
  unsigned short* wqh = xl + E;   unsigned short* wql = wqh + W;
  unsigned short* wkh = wql + W;  unsigned short* wkl = wkh + W;
  unsigned short* wvh = wkl + W;  unsigned short* wvl = wvh + W;
  unsigned short* woh = wvl + W;  unsigned short* wol = woh + W;

  dim3 blk(256);
  dim3 gg(DD / 128, MTOT / 128);   // (16, 32)

  split_hl<<<dim3(2048), blk, 0, stream>>>(x,  xh,  xl,  (int)(E / 8));
  split_hl<<<dim3(2048), blk, 0, stream>>>(wq, wqh, wql, (int)(W / 8));
  split_hl<<<dim3(2048), blk, 0, stream>>>(wk, wkh, wkl, (int)(W / 8));
  split_hl<<<dim3(2048), blk, 0, stream>>>(wv, wvh, wvl, (int)(W / 8));
  split_hl<<<dim3(2048), blk, 0, stream>>>(wo, woh, wol, (int)(W / 8));

  gemm_splitB <<<gg, blk, 0, stream>>>(xh, xl, wqh, wql, Qh, Ql, MTOT, DD, DD);
  gemm_splitB <<<gg, blk, 0, stream>>>(xh, xl, wkh, wkl, Kh, Kl, MTOT, DD, DD);
  gemm_splitBT<<<gg, blk, 0, stream>>>(xh, xl, wvh, wvl, VTh, VTl, MTOT, DD, DD);

  rope_hl<<<dim3((MTOT * 16 * 16) / 256), blk, 0, stream>>>(Qh, Ql, Kh, Kl, fc, fs);

  attn_mfma<<<dim3(SS / 64, HH, BB), blk, 0, stream>>>(Qh, Ql, Kh, Kl, VTh, VTl, xh, xl);

  gemm_split<<<gg, blk, 0, stream>>>(xh, xl, woh, wol, out, MTOT, DD, DD);
}

// Round 9
// 574.263 us; speedup vs baseline: 3.8969x; 1.7042x over previous
//
#include <hip/hip_runtime.h>
#include <cmath>

#define BB 2
#define SS 2048
#define DD 2048
#define HH 16
#define HDD 128
#define MTOT (BB*SS)

typedef float f32x4 __attribute__((ext_vector_type(4)));
typedef short s16x8 __attribute__((ext_vector_type(8)));
typedef short s16x4v __attribute__((ext_vector_type(4)));

static constexpr float NEGV = -1e9f;
static constexpr float SM_SCALE = 0.08838834764831845f; // 1/sqrt(128)

// ---------------------------------------------------------------------------
__device__ __forceinline__ unsigned short f32_to_bf16(float x) {
  unsigned int u = __float_as_uint(x);
  u = u + 0x7FFFu + ((u >> 16) & 1u);
  return (unsigned short)(u >> 16);
}
__device__ __forceinline__ float bf16_to_f32(unsigned short h) {
  return __uint_as_float(((unsigned int)h) << 16);
}
__device__ __forceinline__ void async16(void* ldst, const void* gsrc) {
  __builtin_amdgcn_global_load_lds(
      (const __attribute__((address_space(1))) unsigned int*)gsrc,
      (__attribute__((address_space(3))) unsigned int*)ldst, 16, 0, 0);
}

// ---------------------------------------------------------------------------
// fp32 -> bf16 cast (RNE), 8 elems/thread.
// ---------------------------------------------------------------------------
__global__ __launch_bounds__(256)
void cast_b16(const float* __restrict__ in, unsigned short* __restrict__ out, int n8) {
  int stride = gridDim.x * 256;
  for (int i = blockIdx.x * 256 + threadIdx.x; i < n8; i += stride) {
    const float4* p = (const float4*)in + (size_t)i * 2;
    float4 a = p[0], b = p[1];
    float v[8] = {a.x, a.y, a.z, a.w, b.x, b.y, b.z, b.w};
    s16x8 o;
#pragma unroll
    for (int j = 0; j < 8; ++j) o[j] = (short)f32_to_bf16(v[j]);
    *(s16x8*)(out + (size_t)i * 8) = o;
  }
}

// ---------------------------------------------------------------------------
// Single-term bf16 GEMM: C[M,N] = A[M,K] * B[N,K]^T  (m97 geometry).
// 128x128 tile, BK=32, 4 waves (2x2, 64x64/wave), 16 MFMA/K-step.
// LDS 16 KB: A subtiles 0..7, B subtiles 8..15 (1 KiB fragment-linear each).
// Waves 0,1 stage A halves; waves 2,3 stage B halves (4 async16 each).
// ---------------------------------------------------------------------------
#define GEMM1_BODY                                                             \
  __shared__ unsigned short lds[16 * 512];                                     \
  const int tid = threadIdx.x;                                                 \
  const int l   = tid & 63;                                                    \
  const int w   = tid >> 6;                                                    \
  const int m0  = blockIdx.y * 128;                                            \
  const int n0  = blockIdx.x * 128;                                            \
  const int wm  = w >> 1, wn = w & 1;                                          \
  const unsigned short* mp = (w < 2) ? A : Bm;                                 \
  const int rb = (w < 2) ? m0 : n0;                                            \
  const unsigned short* gs = mp + (size_t)(rb + (w & 1) * 64 + (l & 15)) * K   \
                                + ((l >> 4) * 8);                              \
  unsigned short* ldw = &lds[((w >> 1) * 8 + (w & 1) * 4) * 512];              \
  f32x4 acc[4][4];                                                             \
  _Pragma("unroll") for (int i = 0; i < 4; ++i)                                \
  _Pragma("unroll") for (int j = 0; j < 4; ++j) {                              \
    f32x4 z = {0.f, 0.f, 0.f, 0.f}; acc[i][j] = z; }                           \
  for (int k0 = 0; k0 < K; k0 += 32) {                                         \
    __syncthreads();                                                           \
    _Pragma("unroll") for (int s = 0; s < 4; ++s)                              \
      async16(ldw + s * 512, gs + (size_t)s * 16 * K + k0);                    \
    __syncthreads();                                                           \
    s16x8 ah[4], bh[4];                                                        \
    _Pragma("unroll") for (int i = 0; i < 4; ++i) {                            \
      ah[i] = *(const s16x8*)&lds[(wm * 4 + i) * 512 + l * 8];                 \
      bh[i] = *(const s16x8*)&lds[(8 + wn * 4 + i) * 512 + l * 8];             \
    }                                                                          \
    _Pragma("unroll") for (int i = 0; i < 4; ++i)                              \
    _Pragma("unroll") for (int j = 0; j < 4; ++j)                              \
      acc[i][j] = __builtin_amdgcn_mfma_f32_16x16x32_bf16(ah[i], bh[j], acc[i][j], 0, 0, 0); \
  }                                                                            \
  const int r4 = (l >> 4) * 4, cn = l & 15;

__global__ __launch_bounds__(256)
void gemm_f32(const unsigned short* __restrict__ A, const unsigned short* __restrict__ Bm,
              float* __restrict__ C, int M, int N, int K) {
  GEMM1_BODY
#pragma unroll
  for (int i = 0; i < 4; ++i)
#pragma unroll
    for (int j = 0; j < 4; ++j) {
      float* Cp = C + (size_t)(m0 + wm * 64 + i * 16 + r4) * N + (n0 + wn * 64 + j * 16 + cn);
#pragma unroll
      for (int r = 0; r < 4; ++r) Cp[(size_t)r * N] = acc[i][j][r];
    }
}

__global__ __launch_bounds__(256)
void gemm_b16(const unsigned short* __restrict__ A, const unsigned short* __restrict__ Bm,
              unsigned short* __restrict__ C, int M, int N, int K) {
  GEMM1_BODY
#pragma unroll
  for (int i = 0; i < 4; ++i)
#pragma unroll
    for (int j = 0; j < 4; ++j) {
      size_t idx = (size_t)(m0 + wm * 64 + i * 16 + r4) * N + (n0 + wn * 64 + j * 16 + cn);
#pragma unroll
      for (int r = 0; r < 4; ++r) C[idx + (size_t)r * N] = f32_to_bf16(acc[i][j][r]);
    }
}

// transposed epilogue: C is [N][M] (for V so attention can stage V^T like K/B)
__global__ __launch_bounds__(256)
void gemm_b16T(const unsigned short* __restrict__ A, const unsigned short* __restrict__ Bm,
               unsigned short* __restrict__ C, int M, int N, int K) {
  GEMM1_BODY
#pragma unroll
  for (int i = 0; i < 4; ++i)
#pragma unroll
    for (int j = 0; j < 4; ++j) {
      size_t idxT = (size_t)(n0 + wn * 64 + j * 16 + cn) * M + (m0 + wm * 64 + i * 16 + r4);
      s16x4v hv;
#pragma unroll
      for (int r = 0; r < 4; ++r) hv[r] = (short)f32_to_bf16(acc[i][j][r]);
      *(s16x4v*)&C[idxT] = hv;
    }
}

// ---------------------------------------------------------------------------
// RoPE on bf16 Q and K (interleaved pairs), 8 elems (4 pairs)/thread.
// ---------------------------------------------------------------------------
__global__ __launch_bounds__(256)
void rope_b16(unsigned short* __restrict__ Qb, unsigned short* __restrict__ Kb,
              const float* __restrict__ Fc, const float* __restrict__ Fs) {
  int idx = blockIdx.x * 256 + threadIdx.x;   // < MTOT*16*16
  int m   = idx >> 8;
  int rem = idx & 255;
  int h   = rem >> 4;
  int i4  = rem & 15;
  int s   = m & (SS - 1);
  size_t base = (size_t)m * DD + h * HDD + i4 * 8;
  float4 c  = *(const float4*)&Fc[s * 64 + i4 * 4];
  float4 sn = *(const float4*)&Fs[s * 64 + i4 * 4];
  float cc[4] = {c.x, c.y, c.z, c.w}, ss[4] = {sn.x, sn.y, sn.z, sn.w};
#pragma unroll
  for (int mtx = 0; mtx < 2; ++mtx) {
    unsigned short* Pb = mtx ? Kb : Qb;
    s16x8 v = *(s16x8*)&Pb[base];
    s16x8 o;
#pragma unroll
    for (int p = 0; p < 4; ++p) {
      float re = bf16_to_f32((unsigned short)v[2*p]);
      float im = bf16_to_f32((unsigned short)v[2*p+1]);
      o[2*p]   = (short)f32_to_bf16(re * cc[p] - im * ss[p]);
      o[2*p+1] = (short)f32_to_bf16(re * ss[p] + im * cc[p]);
    }
    *(s16x8*)&Pb[base] = o;
  }
}

// ---------------------------------------------------------------------------
// Flash attention, plain bf16 MFMA, 2-phase double-buffered K/V staging.
// Block = one (qt,h,b); 4 waves x 16 q-rows; Q-tile 64, K-tile 64.
// GRID FIX (round-8 bug): SS/64 = 32 q-tiles -> 1024 blocks total.
// Round-8 decode had sub&63 / qt=63-sub: every block got qt>=32 (out of
// range) -> garbage output. Now: 8 XCDs x 4 (b,h) pairs x 32 q-tiles.
// LDS 72 KiB: K/V tiles double-buffered (16 KiB each) + per-wave P (2 KiB).
// Per tile: issue next tile's global_load_lds BEFORE compute; ONE barrier
// at tile end (vmcnt drain overlaps compute). Canonical layouts
// (round-6-verified): K staged gemm-style, VT staged like K, P packed in
// canonical A-slot order.
// ---------------------------------------------------------------------------
#define KB0_ 0
#define VB0_ 8192
#define KB1_ 16384
#define VB1_ 24576
#define PP_  32768

#define STAGE(BUF, KOFF) do {                                                  \
    const int kd_ = (BUF) ? KB1_ : KB0_;                                       \
    const int vd_ = (BUF) ? VB1_ : VB0_;                                       \
    if (w < 2) {                                                               \
      _Pragma("unroll") for (int i_ = 0; i_ < 8; ++i_) {                       \
        int s_ = (w & 1) * 8 + i_;                                             \
        async16(&lds[kd_ + s_ * 512],                                          \
                sb_ + gsl + (size_t)((KOFF) + (s_ >> 2) * 16) * DD + (s_ & 3) * 32); \
      }                                                                        \
    } else {                                                                   \
      _Pragma("unroll") for (int i_ = 0; i_ < 8; ++i_) {                       \
        int s_ = (w & 1) * 8 + i_;                                             \
        async16(&lds[vd_ + s_ * 512],                                          \
                sb_ + gsl + (size_t)(s_ >> 1) * 16 * MTOT + (KOFF) + (s_ & 1) * 32); \
      }                                                                        \
    }                                                                          \
  } while (0)

__global__ __launch_bounds__(256)
void attn_b16(const unsigned short* __restrict__ Qb, const unsigned short* __restrict__ Kb,
              const unsigned short* __restrict__ VTb, unsigned short* __restrict__ Ob) {
  __shared__ unsigned short lds[36864];  // 72 KiB
  const int tid = threadIdx.x, l = tid & 63, w = tid >> 6;

  // XCD-aware decode (FIXED): each XCD owns 4 (b,h) pairs (K+V = 4MB = one
  // L2); within an XCD, long (high-qt) blocks first for tail balance.
  const int Dd  = blockIdx.x;        // 0..1023
  const int xcd = Dd & 7;
  const int g   = Dd >> 3;           // 0..127
  const int sub = g & 31, ppi = g >> 5;
  const int pair = (xcd << 2) + ppi; // 0..31
  const int h = pair & 15, b = pair >> 4;
  const int qt = 31 - sub;           // 0..31
  const int q0 = qt * 64;
  const int qrow = q0 + w * 16 + ((l >> 4) << 2);

  // ---- Q fragments (registers): lane&15 = q-row, slots (l>>4)*8+e ----
  const size_t rowQ = (size_t)(b * SS + q0 + w * 16 + (l & 15)) * DD + h * HDD + ((l >> 4) * 8);
  s16x8 qf[4];
#pragma unroll
  for (int t = 0; t < 4; ++t) qf[t] = *(const s16x8*)&Qb[rowQ + t * 32];

  // ---- staging source (waves 0,1: K halves; waves 2,3: VT halves) ----
  const unsigned short* sb_;
  size_t gsl;
  if (w < 2) { sb_ = Kb;  gsl = (size_t)(b * SS + (l & 15)) * DD + h * HDD + ((l >> 4) * 8); }
  else       { sb_ = VTb; gsl = (size_t)(h * HDD + (l & 15)) * MTOT + b * SS + ((l >> 4) * 8); }

  f32x4 acc[8];
#pragma unroll
  for (int f = 0; f < 8; ++f) { f32x4 z = {0.f,0.f,0.f,0.f}; acc[f] = z; }
  float m_prev[4], l_run[4];
#pragma unroll
  for (int r = 0; r < 4; ++r) { m_prev[r] = -INFINITY; l_run[r] = 0.f; }

  const int nkt = qt + 1;

  STAGE(0, 0);          // prologue: tile 0 -> buf0
  __syncthreads();      // drains vmcnt: buf0 ready
  int cur = 0;

  for (int t = 0; t < nkt; ++t) {
    const int kb = t * 64;
    if (t + 1 < nkt) STAGE(cur ^ 1, kb + 64);   // issue early, hide under compute
    const int kbase = cur ? KB1_ : KB0_;
    const int vbase = cur ? VB1_ : VB0_;

    // ---- QK^T ----
    float sc[4][4];
    __builtin_amdgcn_s_setprio(1);
#pragma unroll
    for (int sb = 0; sb < 4; ++sb) {
      f32x4 s = {0.f, 0.f, 0.f, 0.f};
#pragma unroll
      for (int tt = 0; tt < 4; ++tt) {
        s16x8 kf = *(const s16x8*)&lds[kbase + (sb * 4 + tt) * 512 + l * 8];
        s = __builtin_amdgcn_mfma_f32_16x16x32_bf16(qf[tt], kf, s, 0, 0, 0);
      }
      int kcol = kb + sb * 16 + (l & 15);
#pragma unroll
      for (int r = 0; r < 4; ++r)
        sc[sb][r] = (kcol <= qrow + r) ? s[r] * SM_SCALE : NEGV;
    }
    __builtin_amdgcn_s_setprio(0);

    // ---- online softmax (per lane: 4 q-rows; reduce over 16 lanes) ----
    float p[4][4];
#pragma unroll
    for (int r = 0; r < 4; ++r) {
      float tm = fmaxf(fmaxf(sc[0][r], sc[1][r]), fmaxf(sc[2][r], sc[3][r]));
      tm = fmaxf(tm, __shfl_xor(tm, 1));
      tm = fmaxf(tm, __shfl_xor(tm, 2));
      tm = fmaxf(tm, __shfl_xor(tm, 4));
      tm = fmaxf(tm, __shfl_xor(tm, 8));
      float mn = fmaxf(m_prev[r], tm);
      float ps = 0.f;
#pragma unroll
      for (int sb = 0; sb < 4; ++sb) { p[sb][r] = __expf(sc[sb][r] - mn); ps += p[sb][r]; }
      ps += __shfl_xor(ps, 1); ps += __shfl_xor(ps, 2);
      ps += __shfl_xor(ps, 4); ps += __shfl_xor(ps, 8);
      float scl = __expf(m_prev[r] - mn);
      l_run[r] = l_run[r] * scl + ps;
      m_prev[r] = mn;
#pragma unroll
      for (int f = 0; f < 8; ++f) acc[f][r] *= scl;
    }

    // ---- pack P (bf16) into canonical A-fragment LDS (round-6 layout) ----
#pragma unroll
    for (int sb = 0; sb < 4; ++sb)
#pragma unroll
      for (int r = 0; r < 4; ++r) {
        int q   = ((l >> 4) << 2) + r;
        int k32 = ((sb & 1) << 4) + (l & 15);
        int off = ((sb >> 1) << 9) + ((q + ((k32 >> 3) << 4)) << 3) + (k32 & 7);
        lds[PP_ + w * 1024 + off] = f32_to_bf16(p[sb][r]);
      }

    // ---- PV: canonical A (P) x canonical B (VT) ----
    s16x8 pa[2];
#pragma unroll
    for (int ks = 0; ks < 2; ++ks)
      pa[ks] = *(const s16x8*)&lds[PP_ + w * 1024 + ks * 512 + l * 8];
    __builtin_amdgcn_s_setprio(1);
#pragma unroll
    for (int dt = 0; dt < 8; ++dt)
#pragma unroll
      for (int ks = 0; ks < 2; ++ks) {
        s16x8 vf = *(const s16x8*)&lds[vbase + (dt * 2 + ks) * 512 + l * 8];
        acc[dt] = __builtin_amdgcn_mfma_f32_16x16x32_bf16(pa[ks], vf, acc[dt], 0, 0, 0);
      }
    __builtin_amdgcn_s_setprio(0);

    __syncthreads();   // drains vmcnt (next buf ready) + protects buf reuse
    cur ^= 1;
  }

  // ---- epilogue: O = acc / l_run -> bf16 ----
  float rl[4];
#pragma unroll
  for (int r = 0; r < 4; ++r) rl[r] = 1.f / l_run[r];
  const size_t orow = (size_t)(b * SS + q0 + w * 16 + ((l >> 4) << 2)) * DD + h * HDD + (l & 15);
#pragma unroll
  for (int f = 0; f < 8; ++f)
#pragma unroll
    for (int r = 0; r < 4; ++r)
      Ob[orow + (size_t)r * DD + f * 16] = f32_to_bf16(acc[f][r] * rl[r]);
}

// ---------------------------------------------------------------------------
extern "C" void kernel_launch(void* const* d_in, const int* in_sizes, int n_in,
                              void* d_out, int out_size, void* d_ws, size_t ws_size,
                              hipStream_t stream) {
  (void)in_sizes; (void)n_in; (void)out_size; (void)ws_size;
  const float* x  = (const float*)d_in[0];
  const float* wq = (const float*)d_in[1];
  const float* wk = (const float*)d_in[2];
  const float* wv = (const float*)d_in[3];
  const float* wo = (const float*)d_in[4];
  const float* fc = (const float*)d_in[5];
  const float* fs = (const float*)d_in[6];
  float* out = (float*)d_out;

  const size_t E = (size_t)MTOT * DD;   // 8.39M elems
  const size_t W = (size_t)DD * DD;     // 4.19M elems

  unsigned short* xb  = (unsigned short*)d_ws;
  unsigned short* Qb  = xb + E;
  unsigned short* Kb  = Qb + E;
  unsigned short* VTb = Kb + E;         // [DD][MTOT] transposed
  unsigned short* Obf = VTb + E;
  unsigned short* wqb = Obf + E;
  unsigned short* wkb = wqb + W;
  unsigned short* wvb = wkb + W;
  unsigned short* wob = wvb + W;

  dim3 blk(256);
  dim3 gg(DD / 128, MTOT / 128);   // (16, 32)

  cast_b16<<<dim3(2048), blk, 0, stream>>>(x,  xb,  (int)(E / 8));
  cast_b16<<<dim3(1024), blk, 0, stream>>>(wq, wqb, (int)(W / 8));
  cast_b16<<<dim3(1024), blk, 0, stream>>>(wk, wkb, (int)(W / 8));
  cast_b16<<<dim3(1024), blk, 0, stream>>>(wv, wvb, (int)(W / 8));
  cast_b16<<<dim3(1024), blk, 0, stream>>>(wo, wob, (int)(W / 8));

  gemm_b16 <<<gg, blk, 0, stream>>>(xb, wqb, Qb,  MTOT, DD, DD);
  gemm_b16 <<<gg, blk, 0, stream>>>(xb, wkb, Kb,  MTOT, DD, DD);
  gemm_b16T<<<gg, blk, 0, stream>>>(xb, wvb, VTb, MTOT, DD, DD);

  rope_b16<<<dim3((MTOT * 16 * 16) / 256), blk, 0, stream>>>(Qb, Kb, fc, fs);

  attn_b16<<<dim3(1024), blk, 0, stream>>>(Qb, Kb, VTb, Obf);   // FIXED grid

  gemm_f32<<<gg, blk, 0, stream>>>(Obf, wob, out, MTOT, DD, DD);
}

// Round 10
// 542.376 us; speedup vs baseline: 4.1260x; 1.0588x over previous
//
#include <hip/hip_runtime.h>
#include <cmath>

#define BB 2
#define SS 2048
#define DD 2048
#define HH 16
#define HDD 128
#define MTOT (BB*SS)

typedef float f32x4 __attribute__((ext_vector_type(4)));
typedef short s16x8 __attribute__((ext_vector_type(8)));
typedef short s16x4v __attribute__((ext_vector_type(4)));

static constexpr float NEGV = -1e9f;
static constexpr float SM_SCALE = 0.08838834764831845f; // 1/sqrt(128)

// ---------------------------------------------------------------------------
__device__ __forceinline__ unsigned short f32_to_bf16(float x) {
  unsigned int u = __float_as_uint(x);
  u = u + 0x7FFFu + ((u >> 16) & 1u);
  return (unsigned short)(u >> 16);
}
__device__ __forceinline__ float bf16_to_f32(unsigned short h) {
  return __uint_as_float(((unsigned int)h) << 16);
}
__device__ __forceinline__ void async16(void* ldst, const void* gsrc) {
  __builtin_amdgcn_global_load_lds(
      (const __attribute__((address_space(1))) unsigned int*)gsrc,
      (__attribute__((address_space(3))) unsigned int*)ldst, 16, 0, 0);
}

// ---------------------------------------------------------------------------
// fp32 -> bf16 casts (RNE), 8 elems/thread.
// ---------------------------------------------------------------------------
__global__ __launch_bounds__(256)
void cast_b16(const float* __restrict__ in, unsigned short* __restrict__ out, int n8) {
  int stride = gridDim.x * 256;
  for (int i = blockIdx.x * 256 + threadIdx.x; i < n8; i += stride) {
    const float4* p = (const float4*)in + (size_t)i * 2;
    float4 a = p[0], b = p[1];
    float v[8] = {a.x, a.y, a.z, a.w, b.x, b.y, b.z, b.w};
    s16x8 o;
#pragma unroll
    for (int j = 0; j < 8; ++j) o[j] = (short)f32_to_bf16(v[j]);
    *(s16x8*)(out + (size_t)i * 8) = o;
  }
}

// all 4 weight matrices in one dispatch (each DD*DD; DD*DD/8 = 2^19)
__global__ __launch_bounds__(256)
void cast_w4(const float* __restrict__ w0, const float* __restrict__ w1,
             const float* __restrict__ w2, const float* __restrict__ w3,
             unsigned short* __restrict__ o0, unsigned short* __restrict__ o1,
             unsigned short* __restrict__ o2, unsigned short* __restrict__ o3) {
  const int per = (DD * DD) / 8;     // 524288 = 2^19
  int stride = gridDim.x * 256;
  for (int i = blockIdx.x * 256 + threadIdx.x; i < 4 * per; i += stride) {
    int which = i >> 19;
    int off = i & (per - 1);
    const float* in = (which == 0) ? w0 : (which == 1) ? w1 : (which == 2) ? w2 : w3;
    unsigned short* out = (which == 0) ? o0 : (which == 1) ? o1 : (which == 2) ? o2 : o3;
    const float4* p = (const float4*)in + (size_t)off * 2;
    float4 a = p[0], b = p[1];
    float v[8] = {a.x, a.y, a.z, a.w, b.x, b.y, b.z, b.w};
    s16x8 o;
#pragma unroll
    for (int j = 0; j < 8; ++j) o[j] = (short)f32_to_bf16(v[j]);
    *(s16x8*)(out + (size_t)off * 8) = o;
  }
}

// ---------------------------------------------------------------------------
// Fused QKV projection GEMM, 2-phase double-buffered (attn-verified pattern).
// C-region select by global n: [0,2048)->Qb, [2048,4096)->Kb, [4096,6144)->VT.
// 128x128 tile, BK=32, 4 waves, 16 MFMA/K-step. LDS 32 KB (2 x 16 KB bufs).
// Grid (48, 32) = 1536 blocks = 6/CU.
// ---------------------------------------------------------------------------
__global__ __launch_bounds__(256)
void gemm_qkv(const unsigned short* __restrict__ A,
              const unsigned short* __restrict__ Wq,
              const unsigned short* __restrict__ Wk,
              const unsigned short* __restrict__ Wv,
              unsigned short* __restrict__ Qb,
              unsigned short* __restrict__ Kb,
              unsigned short* __restrict__ VTb) {
  __shared__ unsigned short lds[32 * 512];   // 32 KiB, two 16 KiB buffers
  const int K = DD;
  const int tid = threadIdx.x, l = tid & 63, w = tid >> 6;
  const int m0  = blockIdx.y * 128;
  const int ng  = blockIdx.x * 128;     // 0..6143
  const int reg = ng >> 11;             // 0:Q 1:K 2:V (block-uniform)
  const int nloc = ng & 2047;
  const int wm = w >> 1, wn = w & 1;
  const unsigned short* Bm = (reg == 0) ? Wq : (reg == 1) ? Wk : Wv;
  const unsigned short* gs = (w < 2)
      ? A  + (size_t)(m0   + (w & 1) * 64 + (l & 15)) * K + ((l >> 4) * 8)
      : Bm + (size_t)(nloc + (w & 1) * 64 + (l & 15)) * K + ((l >> 4) * 8);
  const int ldwoff = ((w >> 1) * 8 + (w & 1) * 4) * 512;

  f32x4 acc[4][4];
#pragma unroll
  for (int i = 0; i < 4; ++i)
#pragma unroll
    for (int j = 0; j < 4; ++j) { f32x4 z = {0.f,0.f,0.f,0.f}; acc[i][j] = z; }

  // prologue: K-step 0 -> buf0
#pragma unroll
  for (int s = 0; s < 4; ++s)
    async16(&lds[ldwoff + s * 512], gs + (size_t)s * 16 * K);
  __syncthreads();
  int cur = 0;

  for (int k0 = 0; k0 < K; k0 += 32) {
    if (k0 + 32 < K) {
#pragma unroll
      for (int s = 0; s < 4; ++s)
        async16(&lds[(cur ^ 1) * 8192 + ldwoff + s * 512],
                gs + (size_t)s * 16 * K + k0 + 32);
    }
    const int base = cur * 8192;
    s16x8 ah[4], bh[4];
#pragma unroll
    for (int i = 0; i < 4; ++i) {
      ah[i] = *(const s16x8*)&lds[base + (wm * 4 + i) * 512 + l * 8];
      bh[i] = *(const s16x8*)&lds[base + (8 + wn * 4 + i) * 512 + l * 8];
    }
#pragma unroll
    for (int i = 0; i < 4; ++i)
#pragma unroll
      for (int j = 0; j < 4; ++j)
        acc[i][j] = __builtin_amdgcn_mfma_f32_16x16x32_bf16(ah[i], bh[j], acc[i][j], 0, 0, 0);
    __syncthreads();   // drains vmcnt (next buf staged) + LDS reads done
    cur ^= 1;
  }

  const int r4 = (l >> 4) * 4, cn = l & 15;
  if (reg < 2) {
    unsigned short* Cb = (reg == 0) ? Qb : Kb;
#pragma unroll
    for (int i = 0; i < 4; ++i)
#pragma unroll
      for (int j = 0; j < 4; ++j) {
        size_t idx = (size_t)(m0 + wm * 64 + i * 16 + r4) * DD + (nloc + wn * 64 + j * 16 + cn);
#pragma unroll
        for (int r = 0; r < 4; ++r) Cb[idx + (size_t)r * DD] = f32_to_bf16(acc[i][j][r]);
      }
  } else {
#pragma unroll
    for (int i = 0; i < 4; ++i)
#pragma unroll
      for (int j = 0; j < 4; ++j) {
        size_t idxT = (size_t)(nloc + wn * 64 + j * 16 + cn) * MTOT + (m0 + wm * 64 + i * 16 + r4);
        s16x4v hv;
#pragma unroll
        for (int r = 0; r < 4; ++r) hv[r] = (short)f32_to_bf16(acc[i][j][r]);
        *(s16x4v*)&VTb[idxT] = hv;
      }
  }
}

// ---------------------------------------------------------------------------
// O-projection GEMM (fp32 out), same 2-phase double-buffered structure.
// ---------------------------------------------------------------------------
__global__ __launch_bounds__(256)
void gemm_o(const unsigned short* __restrict__ A, const unsigned short* __restrict__ Bw,
            float* __restrict__ C) {
  __shared__ unsigned short lds[32 * 512];
  const int K = DD;
  const int tid = threadIdx.x, l = tid & 63, w = tid >> 6;
  const int m0 = blockIdx.y * 128;
  const int n0 = blockIdx.x * 128;
  const int wm = w >> 1, wn = w & 1;
  const unsigned short* gs = (w < 2)
      ? A  + (size_t)(m0 + (w & 1) * 64 + (l & 15)) * K + ((l >> 4) * 8)
      : Bw + (size_t)(n0 + (w & 1) * 64 + (l & 15)) * K + ((l >> 4) * 8);
  const int ldwoff = ((w >> 1) * 8 + (w & 1) * 4) * 512;

  f32x4 acc[4][4];
#pragma unroll
  for (int i = 0; i < 4; ++i)
#pragma unroll
    for (int j = 0; j < 4; ++j) { f32x4 z = {0.f,0.f,0.f,0.f}; acc[i][j] = z; }

#pragma unroll
  for (int s = 0; s < 4; ++s)
    async16(&lds[ldwoff + s * 512], gs + (size_t)s * 16 * K);
  __syncthreads();
  int cur = 0;

  for (int k0 = 0; k0 < K; k0 += 32) {
    if (k0 + 32 < K) {
#pragma unroll
      for (int s = 0; s < 4; ++s)
        async16(&lds[(cur ^ 1) * 8192 + ldwoff + s * 512],
                gs + (size_t)s * 16 * K + k0 + 32);
    }
    const int base = cur * 8192;
    s16x8 ah[4], bh[4];
#pragma unroll
    for (int i = 0; i < 4; ++i) {
      ah[i] = *(const s16x8*)&lds[base + (wm * 4 + i) * 512 + l * 8];
      bh[i] = *(const s16x8*)&lds[base + (8 + wn * 4 + i) * 512 + l * 8];
    }
#pragma unroll
    for (int i = 0; i < 4; ++i)
#pragma unroll
      for (int j = 0; j < 4; ++j)
        acc[i][j] = __builtin_amdgcn_mfma_f32_16x16x32_bf16(ah[i], bh[j], acc[i][j], 0, 0, 0);
    __syncthreads();
    cur ^= 1;
  }

  const int r4 = (l >> 4) * 4, cn = l & 15;
#pragma unroll
  for (int i = 0; i < 4; ++i)
#pragma unroll
    for (int j = 0; j < 4; ++j) {
      float* Cp = C + (size_t)(m0 + wm * 64 + i * 16 + r4) * DD + (n0 + wn * 64 + j * 16 + cn);
#pragma unroll
      for (int r = 0; r < 4; ++r) Cp[(size_t)r * DD] = acc[i][j][r];
    }
}

// ---------------------------------------------------------------------------
// RoPE on bf16 Q and K (interleaved pairs), 8 elems (4 pairs)/thread.
// ---------------------------------------------------------------------------
__global__ __launch_bounds__(256)
void rope_b16(unsigned short* __restrict__ Qb, unsigned short* __restrict__ Kb,
              const float* __restrict__ Fc, const float* __restrict__ Fs) {
  int idx = blockIdx.x * 256 + threadIdx.x;   // < MTOT*16*16
  int m   = idx >> 8;
  int rem = idx & 255;
  int h   = rem >> 4;
  int i4  = rem & 15;
  int s   = m & (SS - 1);
  size_t base = (size_t)m * DD + h * HDD + i4 * 8;
  float4 c  = *(const float4*)&Fc[s * 64 + i4 * 4];
  float4 sn = *(const float4*)&Fs[s * 64 + i4 * 4];
  float cc[4] = {c.x, c.y, c.z, c.w}, ss[4] = {sn.x, sn.y, sn.z, sn.w};
#pragma unroll
  for (int mtx = 0; mtx < 2; ++mtx) {
    unsigned short* Pb = mtx ? Kb : Qb;
    s16x8 v = *(s16x8*)&Pb[base];
    s16x8 o;
#pragma unroll
    for (int p = 0; p < 4; ++p) {
      float re = bf16_to_f32((unsigned short)v[2*p]);
      float im = bf16_to_f32((unsigned short)v[2*p+1]);
      o[2*p]   = (short)f32_to_bf16(re * cc[p] - im * ss[p]);
      o[2*p+1] = (short)f32_to_bf16(re * ss[p] + im * cc[p]);
    }
    *(s16x8*)&Pb[base] = o;
  }
}

// ---------------------------------------------------------------------------
// Flash attention, plain bf16 MFMA, 2-phase double-buffered K/V staging.
// UNCHANGED from round-9 (verified: 143 us, absmax 0.0156).
// ---------------------------------------------------------------------------
#define KB0_ 0
#define VB0_ 8192
#define KB1_ 16384
#define VB1_ 24576
#define PP_  32768

#define STAGE(BUF, KOFF) do {                                                  \
    const int kd_ = (BUF) ? KB1_ : KB0_;                                       \
    const int vd_ = (BUF) ? VB1_ : VB0_;                                       \
    if (w < 2) {                                                               \
      _Pragma("unroll") for (int i_ = 0; i_ < 8; ++i_) {                       \
        int s_ = (w & 1) * 8 + i_;                                             \
        async16(&lds[kd_ + s_ * 512],                                          \
                sb_ + gsl + (size_t)((KOFF) + (s_ >> 2) * 16) * DD + (s_ & 3) * 32); \
      }                                                                        \
    } else {                                                                   \
      _Pragma("unroll") for (int i_ = 0; i_ < 8; ++i_) {                       \
        int s_ = (w & 1) * 8 + i_;                                             \
        async16(&lds[vd_ + s_ * 512],                                          \
                sb_ + gsl + (size_t)(s_ >> 1) * 16 * MTOT + (KOFF) + (s_ & 1) * 32); \
      }                                                                        \
    }                                                                          \
  } while (0)

__global__ __launch_bounds__(256)
void attn_b16(const unsigned short* __restrict__ Qb, const unsigned short* __restrict__ Kb,
              const unsigned short* __restrict__ VTb, unsigned short* __restrict__ Ob) {
  __shared__ unsigned short lds[36864];  // 72 KiB
  const int tid = threadIdx.x, l = tid & 63, w = tid >> 6;

  const int Dd  = blockIdx.x;        // 0..1023
  const int xcd = Dd & 7;
  const int g   = Dd >> 3;           // 0..127
  const int sub = g & 31, ppi = g >> 5;
  const int pair = (xcd << 2) + ppi; // 0..31
  const int h = pair & 15, b = pair >> 4;
  const int qt = 31 - sub;           // 0..31
  const int q0 = qt * 64;
  const int qrow = q0 + w * 16 + ((l >> 4) << 2);

  const size_t rowQ = (size_t)(b * SS + q0 + w * 16 + (l & 15)) * DD + h * HDD + ((l >> 4) * 8);
  s16x8 qf[4];
#pragma unroll
  for (int t = 0; t < 4; ++t) qf[t] = *(const s16x8*)&Qb[rowQ + t * 32];

  const unsigned short* sb_;
  size_t gsl;
  if (w < 2) { sb_ = Kb;  gsl = (size_t)(b * SS + (l & 15)) * DD + h * HDD + ((l >> 4) * 8); }
  else       { sb_ = VTb; gsl = (size_t)(h * HDD + (l & 15)) * MTOT + b * SS + ((l >> 4) * 8); }

  f32x4 acc[8];
#pragma unroll
  for (int f = 0; f < 8; ++f) { f32x4 z = {0.f,0.f,0.f,0.f}; acc[f] = z; }
  float m_prev[4], l_run[4];
#pragma unroll
  for (int r = 0; r < 4; ++r) { m_prev[r] = -INFINITY; l_run[r] = 0.f; }

  const int nkt = qt + 1;

  STAGE(0, 0);
  __syncthreads();
  int cur = 0;

  for (int t = 0; t < nkt; ++t) {
    const int kb = t * 64;
    if (t + 1 < nkt) STAGE(cur ^ 1, kb + 64);
    const int kbase = cur ? KB1_ : KB0_;
    const int vbase = cur ? VB1_ : VB0_;

    float sc[4][4];
    __builtin_amdgcn_s_setprio(1);
#pragma unroll
    for (int sb = 0; sb < 4; ++sb) {
      f32x4 s = {0.f, 0.f, 0.f, 0.f};
#pragma unroll
      for (int tt = 0; tt < 4; ++tt) {
        s16x8 kf = *(const s16x8*)&lds[kbase + (sb * 4 + tt) * 512 + l * 8];
        s = __builtin_amdgcn_mfma_f32_16x16x32_bf16(qf[tt], kf, s, 0, 0, 0);
      }
      int kcol = kb + sb * 16 + (l & 15);
#pragma unroll
      for (int r = 0; r < 4; ++r)
        sc[sb][r] = (kcol <= qrow + r) ? s[r] * SM_SCALE : NEGV;
    }
    __builtin_amdgcn_s_setprio(0);

    float p[4][4];
#pragma unroll
    for (int r = 0; r < 4; ++r) {
      float tm = fmaxf(fmaxf(sc[0][r], sc[1][r]), fmaxf(sc[2][r], sc[3][r]));
      tm = fmaxf(tm, __shfl_xor(tm, 1));
      tm = fmaxf(tm, __shfl_xor(tm, 2));
      tm = fmaxf(tm, __shfl_xor(tm, 4));
      tm = fmaxf(tm, __shfl_xor(tm, 8));
      float mn = fmaxf(m_prev[r], tm);
      float ps = 0.f;
#pragma unroll
      for (int sb = 0; sb < 4; ++sb) { p[sb][r] = __expf(sc[sb][r] - mn); ps += p[sb][r]; }
      ps += __shfl_xor(ps, 1); ps += __shfl_xor(ps, 2);
      ps += __shfl_xor(ps, 4); ps += __shfl_xor(ps, 8);
      float scl = __expf(m_prev[r] - mn);
      l_run[r] = l_run[r] * scl + ps;
      m_prev[r] = mn;
#pragma unroll
      for (int f = 0; f < 8; ++f) acc[f][r] *= scl;
    }

#pragma unroll
    for (int sb = 0; sb < 4; ++sb)
#pragma unroll
      for (int r = 0; r < 4; ++r) {
        int q   = ((l >> 4) << 2) + r;
        int k32 = ((sb & 1) << 4) + (l & 15);
        int off = ((sb >> 1) << 9) + ((q + ((k32 >> 3) << 4)) << 3) + (k32 & 7);
        lds[PP_ + w * 1024 + off] = f32_to_bf16(p[sb][r]);
      }

    s16x8 pa[2];
#pragma unroll
    for (int ks = 0; ks < 2; ++ks)
      pa[ks] = *(const s16x8*)&lds[PP_ + w * 1024 + ks * 512 + l * 8];
    __builtin_amdgcn_s_setprio(1);
#pragma unroll
    for (int dt = 0; dt < 8; ++dt)
#pragma unroll
      for (int ks = 0; ks < 2; ++ks) {
        s16x8 vf = *(const s16x8*)&lds[vbase + (dt * 2 + ks) * 512 + l * 8];
        acc[dt] = __builtin_amdgcn_mfma_f32_16x16x32_bf16(pa[ks], vf, acc[dt], 0, 0, 0);
      }
    __builtin_amdgcn_s_setprio(0);

    __syncthreads();
    cur ^= 1;
  }

  float rl[4];
#pragma unroll
  for (int r = 0; r < 4; ++r) rl[r] = 1.f / l_run[r];
  const size_t orow = (size_t)(b * SS + q0 + w * 16 + ((l >> 4) << 2)) * DD + h * HDD + (l & 15);
#pragma unroll
  for (int f = 0; f < 8; ++f)
#pragma unroll
    for (int r = 0; r < 4; ++r)
      Ob[orow + (size_t)r * DD + f * 16] = f32_to_bf16(acc[f][r] * rl[r]);
}

// ---------------------------------------------------------------------------
extern "C" void kernel_launch(void* const* d_in, const int* in_sizes, int n_in,
                              void* d_out, int out_size, void* d_ws, size_t ws_size,
                              hipStream_t stream) {
  (void)in_sizes; (void)n_in; (void)out_size; (void)ws_size;
  const float* x  = (const float*)d_in[0];
  const float* wq = (const float*)d_in[1];
  const float* wk = (const float*)d_in[2];
  const float* wv = (const float*)d_in[3];
  const float* wo = (const float*)d_in[4];
  const float* fc = (const float*)d_in[5];
  const float* fs = (const float*)d_in[6];
  float* out = (float*)d_out;

  const size_t E = (size_t)MTOT * DD;   // 8.39M elems
  const size_t W = (size_t)DD * DD;     // 4.19M elems

  unsigned short* xb  = (unsigned short*)d_ws;
  unsigned short* Qb  = xb + E;
  unsigned short* Kb  = Qb + E;
  unsigned short* VTb = Kb + E;         // [DD][MTOT] transposed
  unsigned short* Obf = VTb + E;
  unsigned short* wqb = Obf + E;
  unsigned short* wkb = wqb + W;
  unsigned short* wvb = wkb + W;
  unsigned short* wob = wvb + W;

  dim3 blk(256);

  cast_b16<<<dim3(2048), blk, 0, stream>>>(x, xb, (int)(E / 8));
  cast_w4<<<dim3(2048), blk, 0, stream>>>(wq, wk, wv, wo, wqb, wkb, wvb, wob);

  gemm_qkv<<<dim3(3 * DD / 128, MTOT / 128), blk, 0, stream>>>(
      xb, wqb, wkb, wvb, Qb, Kb, VTb);                     // (48, 32)

  rope_b16<<<dim3((MTOT * 16 * 16) / 256), blk, 0, stream>>>(Qb, Kb, fc, fs);

  attn_b16<<<dim3(1024), blk, 0, stream>>>(Qb, Kb, VTb, Obf);

  gemm_o<<<dim3(DD / 128, MTOT / 128), blk, 0, stream>>>(Obf, wob, out);  // (16, 32)
}

// Round 11
// 539.334 us; speedup vs baseline: 4.1493x; 1.0056x over previous
//
#include <hip/hip_runtime.h>
#include <cmath>

#define BB 2
#define SS 2048
#define DD 2048
#define HH 16
#define HDD 128
#define MTOT (BB*SS)

typedef float f32x4 __attribute__((ext_vector_type(4)));
typedef short s16x8 __attribute__((ext_vector_type(8)));
typedef short s16x4v __attribute__((ext_vector_type(4)));

static constexpr float NEGV = -1e9f;
static constexpr float SM_SCALE = 0.08838834764831845f; // 1/sqrt(128)

// ---------------------------------------------------------------------------
__device__ __forceinline__ unsigned short f32_to_bf16(float x) {
  unsigned int u = __float_as_uint(x);
  u = u + 0x7FFFu + ((u >> 16) & 1u);
  return (unsigned short)(u >> 16);
}
__device__ __forceinline__ float bf16_to_f32(unsigned short h) {
  return __uint_as_float(((unsigned int)h) << 16);
}
__device__ __forceinline__ void async16(void* ldst, const void* gsrc) {
  __builtin_amdgcn_global_load_lds(
      (const __attribute__((address_space(1))) unsigned int*)gsrc,
      (__attribute__((address_space(3))) unsigned int*)ldst, 16, 0, 0);
}

// ---------------------------------------------------------------------------
// fp32 -> bf16 casts (RNE), 8 elems/thread.
// ---------------------------------------------------------------------------
__global__ __launch_bounds__(256)
void cast_b16(const float* __restrict__ in, unsigned short* __restrict__ out, int n8) {
  int stride = gridDim.x * 256;
  for (int i = blockIdx.x * 256 + threadIdx.x; i < n8; i += stride) {
    const float4* p = (const float4*)in + (size_t)i * 2;
    float4 a = p[0], b = p[1];
    float v[8] = {a.x, a.y, a.z, a.w, b.x, b.y, b.z, b.w};
    s16x8 o;
#pragma unroll
    for (int j = 0; j < 8; ++j) o[j] = (short)f32_to_bf16(v[j]);
    *(s16x8*)(out + (size_t)i * 8) = o;
  }
}

__global__ __launch_bounds__(256)
void cast_w4(const float* __restrict__ w0, const float* __restrict__ w1,
             const float* __restrict__ w2, const float* __restrict__ w3,
             unsigned short* __restrict__ o0, unsigned short* __restrict__ o1,
             unsigned short* __restrict__ o2, unsigned short* __restrict__ o3) {
  const int per = (DD * DD) / 8;     // 524288 = 2^19
  int stride = gridDim.x * 256;
  for (int i = blockIdx.x * 256 + threadIdx.x; i < 4 * per; i += stride) {
    int which = i >> 19;
    int off = i & (per - 1);
    const float* in = (which == 0) ? w0 : (which == 1) ? w1 : (which == 2) ? w2 : w3;
    unsigned short* out = (which == 0) ? o0 : (which == 1) ? o1 : (which == 2) ? o2 : o3;
    const float4* p = (const float4*)in + (size_t)off * 2;
    float4 a = p[0], b = p[1];
    float v[8] = {a.x, a.y, a.z, a.w, b.x, b.y, b.z, b.w};
    s16x8 o;
#pragma unroll
    for (int j = 0; j < 8; ++j) o[j] = (short)f32_to_bf16(v[j]);
    *(s16x8*)(out + (size_t)off * 8) = o;
  }
}

// ---------------------------------------------------------------------------
// Deep-pipelined bf16 GEMM core (T3/T4): 128x128 tile, BK=32, 4 waves,
// FOUR 16 KiB LDS buffers, stage 3 tiles ahead, counted s_waitcnt vmcnt(8)
// + raw s_barrier per K-step (never drain to 0 in steady state).
// Safety: each wave stages its own 1/4 of every tile -> own-vmcnt(8)+barrier
// ==> tile t fully resident. Stage of t+3 hits buf[(t-1)&3] whose readers
// all passed barrier t (no WAR). Tail peels with vmcnt(4)/vmcnt(0).
// ---------------------------------------------------------------------------
#define GEMMDP_LOOP                                                            \
  f32x4 acc[4][4];                                                             \
  _Pragma("unroll") for (int i = 0; i < 4; ++i)                                \
  _Pragma("unroll") for (int j = 0; j < 4; ++j) {                              \
    f32x4 z = {0.f, 0.f, 0.f, 0.f}; acc[i][j] = z; }                           \
  const int nk = K / 32;                                                       \
  _Pragma("unroll") for (int pt = 0; pt < 3; ++pt)                             \
    _Pragma("unroll") for (int s = 0; s < 4; ++s)                              \
      async16(&lds[pt * 8192 + ldwoff + s * 512],                              \
              gs + (size_t)s * 16 * K + pt * 32);                              \
  for (int t = 0; t < nk; ++t) {                                               \
    if (t + 2 < nk)      asm volatile("s_waitcnt vmcnt(8)" ::: "memory");      \
    else if (t + 1 < nk) asm volatile("s_waitcnt vmcnt(4)" ::: "memory");      \
    else                 asm volatile("s_waitcnt vmcnt(0)" ::: "memory");      \
    __builtin_amdgcn_s_barrier();                                              \
    const int base = (t & 3) * 8192;                                           \
    s16x8 ah[4], bh[4];                                                        \
    _Pragma("unroll") for (int i = 0; i < 4; ++i) {                            \
      ah[i] = *(const s16x8*)&lds[base + (wm * 4 + i) * 512 + l * 8];          \
      bh[i] = *(const s16x8*)&lds[base + (8 + wn * 4 + i) * 512 + l * 8];      \
    }                                                                          \
    _Pragma("unroll") for (int i = 0; i < 4; ++i)                              \
    _Pragma("unroll") for (int j = 0; j < 4; ++j)                              \
      acc[i][j] = __builtin_amdgcn_mfma_f32_16x16x32_bf16(ah[i], bh[j], acc[i][j], 0, 0, 0); \
    if (t + 3 < nk)                                                            \
      _Pragma("unroll") for (int s = 0; s < 4; ++s)                            \
        async16(&lds[((t + 3) & 3) * 8192 + ldwoff + s * 512],                 \
                gs + (size_t)s * 16 * K + (size_t)(t + 3) * 32);               \
  }

// ---------------------------------------------------------------------------
// Fused QKV projection GEMM (deep-pipelined). Grid (48, 32).
// C-region select by global n: [0,2048)->Qb, [2048,4096)->Kb, [4096,6144)->VT.
// ---------------------------------------------------------------------------
__global__ __launch_bounds__(256)
void gemm_qkv(const unsigned short* __restrict__ A,
              const unsigned short* __restrict__ Wq,
              const unsigned short* __restrict__ Wk,
              const unsigned short* __restrict__ Wv,
              unsigned short* __restrict__ Qb,
              unsigned short* __restrict__ Kb,
              unsigned short* __restrict__ VTb) {
  __shared__ unsigned short lds[64 * 512];   // 64 KiB, four 16 KiB buffers
  const int K = DD;
  const int tid = threadIdx.x, l = tid & 63, w = tid >> 6;
  const int m0  = blockIdx.y * 128;
  const int ng  = blockIdx.x * 128;     // 0..6143
  const int reg = ng >> 11;             // 0:Q 1:K 2:V (block-uniform)
  const int nloc = ng & 2047;
  const int wm = w >> 1, wn = w & 1;
  const unsigned short* Bm = (reg == 0) ? Wq : (reg == 1) ? Wk : Wv;
  const unsigned short* gs = (w < 2)
      ? A  + (size_t)(m0   + (w & 1) * 64 + (l & 15)) * K + ((l >> 4) * 8)
      : Bm + (size_t)(nloc + (w & 1) * 64 + (l & 15)) * K + ((l >> 4) * 8);
  const int ldwoff = ((w >> 1) * 8 + (w & 1) * 4) * 512;

  GEMMDP_LOOP

  const int r4 = (l >> 4) * 4, cn = l & 15;
  if (reg < 2) {
    unsigned short* Cb = (reg == 0) ? Qb : Kb;
#pragma unroll
    for (int i = 0; i < 4; ++i)
#pragma unroll
      for (int j = 0; j < 4; ++j) {
        size_t idx = (size_t)(m0 + wm * 64 + i * 16 + r4) * DD + (nloc + wn * 64 + j * 16 + cn);
#pragma unroll
        for (int r = 0; r < 4; ++r) Cb[idx + (size_t)r * DD] = f32_to_bf16(acc[i][j][r]);
      }
  } else {
#pragma unroll
    for (int i = 0; i < 4; ++i)
#pragma unroll
      for (int j = 0; j < 4; ++j) {
        size_t idxT = (size_t)(nloc + wn * 64 + j * 16 + cn) * MTOT + (m0 + wm * 64 + i * 16 + r4);
        s16x4v hv;
#pragma unroll
        for (int r = 0; r < 4; ++r) hv[r] = (short)f32_to_bf16(acc[i][j][r]);
        *(s16x4v*)&VTb[idxT] = hv;
      }
  }
}

// ---------------------------------------------------------------------------
// O-projection GEMM (fp32 out), deep-pipelined. Grid (16, 32).
// ---------------------------------------------------------------------------
__global__ __launch_bounds__(256)
void gemm_o(const unsigned short* __restrict__ A, const unsigned short* __restrict__ Bw,
            float* __restrict__ C) {
  __shared__ unsigned short lds[64 * 512];
  const int K = DD;
  const int tid = threadIdx.x, l = tid & 63, w = tid >> 6;
  const int m0 = blockIdx.y * 128;
  const int n0 = blockIdx.x * 128;
  const int wm = w >> 1, wn = w & 1;
  const unsigned short* gs = (w < 2)
      ? A  + (size_t)(m0 + (w & 1) * 64 + (l & 15)) * K + ((l >> 4) * 8)
      : Bw + (size_t)(n0 + (w & 1) * 64 + (l & 15)) * K + ((l >> 4) * 8);
  const int ldwoff = ((w >> 1) * 8 + (w & 1) * 4) * 512;

  GEMMDP_LOOP

  const int r4 = (l >> 4) * 4, cn = l & 15;
#pragma unroll
  for (int i = 0; i < 4; ++i)
#pragma unroll
    for (int j = 0; j < 4; ++j) {
      float* Cp = C + (size_t)(m0 + wm * 64 + i * 16 + r4) * DD + (n0 + wn * 64 + j * 16 + cn);
#pragma unroll
      for (int r = 0; r < 4; ++r) Cp[(size_t)r * DD] = acc[i][j][r];
    }
}

// ---------------------------------------------------------------------------
// RoPE on bf16 Q and K (interleaved pairs), 8 elems (4 pairs)/thread.
// ---------------------------------------------------------------------------
__global__ __launch_bounds__(256)
void rope_b16(unsigned short* __restrict__ Qb, unsigned short* __restrict__ Kb,
              const float* __restrict__ Fc, const float* __restrict__ Fs) {
  int idx = blockIdx.x * 256 + threadIdx.x;   // < MTOT*16*16
  int m   = idx >> 8;
  int rem = idx & 255;
  int h   = rem >> 4;
  int i4  = rem & 15;
  int s   = m & (SS - 1);
  size_t base = (size_t)m * DD + h * HDD + i4 * 8;
  float4 c  = *(const float4*)&Fc[s * 64 + i4 * 4];
  float4 sn = *(const float4*)&Fs[s * 64 + i4 * 4];
  float cc[4] = {c.x, c.y, c.z, c.w}, ss[4] = {sn.x, sn.y, sn.z, sn.w};
#pragma unroll
  for (int mtx = 0; mtx < 2; ++mtx) {
    unsigned short* Pb = mtx ? Kb : Qb;
    s16x8 v = *(s16x8*)&Pb[base];
    s16x8 o;
#pragma unroll
    for (int p = 0; p < 4; ++p) {
      float re = bf16_to_f32((unsigned short)v[2*p]);
      float im = bf16_to_f32((unsigned short)v[2*p+1]);
      o[2*p]   = (short)f32_to_bf16(re * cc[p] - im * ss[p]);
      o[2*p+1] = (short)f32_to_bf16(re * ss[p] + im * cc[p]);
    }
    *(s16x8*)&Pb[base] = o;
  }
}

// ---------------------------------------------------------------------------
// Flash attention, plain bf16 MFMA, 2-phase double-buffered K/V staging.
// UNCHANGED from round-9 (verified: 143 us, absmax 0.0156).
// ---------------------------------------------------------------------------
#define KB0_ 0
#define VB0_ 8192
#define KB1_ 16384
#define VB1_ 24576
#define PP_  32768

#define STAGE(BUF, KOFF) do {                                                  \
    const int kd_ = (BUF) ? KB1_ : KB0_;                                       \
    const int vd_ = (BUF) ? VB1_ : VB0_;                                       \
    if (w < 2) {                                                               \
      _Pragma("unroll") for (int i_ = 0; i_ < 8; ++i_) {                       \
        int s_ = (w & 1) * 8 + i_;                                             \
        async16(&lds[kd_ + s_ * 512],                                          \
                sb_ + gsl + (size_t)((KOFF) + (s_ >> 2) * 16) * DD + (s_ & 3) * 32); \
      }                                                                        \
    } else {                                                                   \
      _Pragma("unroll") for (int i_ = 0; i_ < 8; ++i_) {                       \
        int s_ = (w & 1) * 8 + i_;                                             \
        async16(&lds[vd_ + s_ * 512],                                          \
                sb_ + gsl + (size_t)(s_ >> 1) * 16 * MTOT + (KOFF) + (s_ & 1) * 32); \
      }                                                                        \
    }                                                                          \
  } while (0)

__global__ __launch_bounds__(256)
void attn_b16(const unsigned short* __restrict__ Qb, const unsigned short* __restrict__ Kb,
              const unsigned short* __restrict__ VTb, unsigned short* __restrict__ Ob) {
  __shared__ unsigned short lds[36864];  // 72 KiB
  const int tid = threadIdx.x, l = tid & 63, w = tid >> 6;

  const int Dd  = blockIdx.x;        // 0..1023
  const int xcd = Dd & 7;
  const int g   = Dd >> 3;           // 0..127
  const int sub = g & 31, ppi = g >> 5;
  const int pair = (xcd << 2) + ppi; // 0..31
  const int h = pair & 15, b = pair >> 4;
  const int qt = 31 - sub;           // 0..31
  const int q0 = qt * 64;
  const int qrow = q0 + w * 16 + ((l >> 4) << 2);

  const size_t rowQ = (size_t)(b * SS + q0 + w * 16 + (l & 15)) * DD + h * HDD + ((l >> 4) * 8);
  s16x8 qf[4];
#pragma unroll
  for (int t = 0; t < 4; ++t) qf[t] = *(const s16x8*)&Qb[rowQ + t * 32];

  const unsigned short* sb_;
  size_t gsl;
  if (w < 2) { sb_ = Kb;  gsl = (size_t)(b * SS + (l & 15)) * DD + h * HDD + ((l >> 4) * 8); }
  else       { sb_ = VTb; gsl = (size_t)(h * HDD + (l & 15)) * MTOT + b * SS + ((l >> 4) * 8); }

  f32x4 acc[8];
#pragma unroll
  for (int f = 0; f < 8; ++f) { f32x4 z = {0.f,0.f,0.f,0.f}; acc[f] = z; }
  float m_prev[4], l_run[4];
#pragma unroll
  for (int r = 0; r < 4; ++r) { m_prev[r] = -INFINITY; l_run[r] = 0.f; }

  const int nkt = qt + 1;

  STAGE(0, 0);
  __syncthreads();
  int cur = 0;

  for (int t = 0; t < nkt; ++t) {
    const int kb = t * 64;
    if (t + 1 < nkt) STAGE(cur ^ 1, kb + 64);
    const int kbase = cur ? KB1_ : KB0_;
    const int vbase = cur ? VB1_ : VB0_;

    float sc[4][4];
    __builtin_amdgcn_s_setprio(1);
#pragma unroll
    for (int sb = 0; sb < 4; ++sb) {
      f32x4 s = {0.f, 0.f, 0.f, 0.f};
#pragma unroll
      for (int tt = 0; tt < 4; ++tt) {
        s16x8 kf = *(const s16x8*)&lds[kbase + (sb * 4 + tt) * 512 + l * 8];
        s = __builtin_amdgcn_mfma_f32_16x16x32_bf16(qf[tt], kf, s, 0, 0, 0);
      }
      int kcol = kb + sb * 16 + (l & 15);
#pragma unroll
      for (int r = 0; r < 4; ++r)
        sc[sb][r] = (kcol <= qrow + r) ? s[r] * SM_SCALE : NEGV;
    }
    __builtin_amdgcn_s_setprio(0);

    float p[4][4];
#pragma unroll
    for (int r = 0; r < 4; ++r) {
      float tm = fmaxf(fmaxf(sc[0][r], sc[1][r]), fmaxf(sc[2][r], sc[3][r]));
      tm = fmaxf(tm, __shfl_xor(tm, 1));
      tm = fmaxf(tm, __shfl_xor(tm, 2));
      tm = fmaxf(tm, __shfl_xor(tm, 4));
      tm = fmaxf(tm, __shfl_xor(tm, 8));
      float mn = fmaxf(m_prev[r], tm);
      float ps = 0.f;
#pragma unroll
      for (int sb = 0; sb < 4; ++sb) { p[sb][r] = __expf(sc[sb][r] - mn); ps += p[sb][r]; }
      ps += __shfl_xor(ps, 1); ps += __shfl_xor(ps, 2);
      ps += __shfl_xor(ps, 4); ps += __shfl_xor(ps, 8);
      float scl = __expf(m_prev[r] - mn);
      l_run[r] = l_run[r] * scl + ps;
      m_prev[r] = mn;
#pragma unroll
      for (int f = 0; f < 8; ++f) acc[f][r] *= scl;
    }

#pragma unroll
    for (int sb = 0; sb < 4; ++sb)
#pragma unroll
      for (int r = 0; r < 4; ++r) {
        int q   = ((l >> 4) << 2) + r;
        int k32 = ((sb & 1) << 4) + (l & 15);
        int off = ((sb >> 1) << 9) + ((q + ((k32 >> 3) << 4)) << 3) + (k32 & 7);
        lds[PP_ + w * 1024 + off] = f32_to_bf16(p[sb][r]);
      }

    s16x8 pa[2];
#pragma unroll
    for (int ks = 0; ks < 2; ++ks)
      pa[ks] = *(const s16x8*)&lds[PP_ + w * 1024 + ks * 512 + l * 8];
    __builtin_amdgcn_s_setprio(1);
#pragma unroll
    for (int dt = 0; dt < 8; ++dt)
#pragma unroll
      for (int ks = 0; ks < 2; ++ks) {
        s16x8 vf = *(const s16x8*)&lds[vbase + (dt * 2 + ks) * 512 + l * 8];
        acc[dt] = __builtin_amdgcn_mfma_f32_16x16x32_bf16(pa[ks], vf, acc[dt], 0, 0, 0);
      }
    __builtin_amdgcn_s_setprio(0);

    __syncthreads();
    cur ^= 1;
  }

  float rl[4];
#pragma unroll
  for (int r = 0; r < 4; ++r) rl[r] = 1.f / l_run[r];
  const size_t orow = (size_t)(b * SS + q0 + w * 16 + ((l >> 4) << 2)) * DD + h * HDD + (l & 15);
#pragma unroll
  for (int f = 0; f < 8; ++f)
#pragma unroll
    for (int r = 0; r < 4; ++r)
      Ob[orow + (size_t)r * DD + f * 16] = f32_to_bf16(acc[f][r] * rl[r]);
}

// ---------------------------------------------------------------------------
extern "C" void kernel_launch(void* const* d_in, const int* in_sizes, int n_in,
                              void* d_out, int out_size, void* d_ws, size_t ws_size,
                              hipStream_t stream) {
  (void)in_sizes; (void)n_in; (void)out_size; (void)ws_size;
  const float* x  = (const float*)d_in[0];
  const float* wq = (const float*)d_in[1];
  const float* wk = (const float*)d_in[2];
  const float* wv = (const float*)d_in[3];
  const float* wo = (const float*)d_in[4];
  const float* fc = (const float*)d_in[5];
  const float* fs = (const float*)d_in[6];
  float* out = (float*)d_out;

  const size_t E = (size_t)MTOT * DD;   // 8.39M elems
  const size_t W = (size_t)DD * DD;     // 4.19M elems

  unsigned short* xb  = (unsigned short*)d_ws;
  unsigned short* Qb  = xb + E;
  unsigned short* Kb  = Qb + E;
  unsigned short* VTb = Kb + E;         // [DD][MTOT] transposed
  unsigned short* Obf = VTb + E;
  unsigned short* wqb = Obf + E;
  unsigned short* wkb = wqb + W;
  unsigned short* wvb = wkb + W;
  unsigned short* wob = wvb + W;

  dim3 blk(256);

  cast_b16<<<dim3(2048), blk, 0, stream>>>(x, xb, (int)(E / 8));
  cast_w4<<<dim3(2048), blk, 0, stream>>>(wq, wk, wv, wo, wqb, wkb, wvb, wob);

  gemm_qkv<<<dim3(3 * DD / 128, MTOT / 128), blk, 0, stream>>>(
      xb, wqb, wkb, wvb, Qb, Kb, VTb);                     // (48, 32)

  rope_b16<<<dim3((MTOT * 16 * 16) / 256), blk, 0, stream>>>(Qb, Kb, fc, fs);

  attn_b16<<<dim3(1024), blk, 0, stream>>>(Qb, Kb, VTb, Obf);

  gemm_o<<<dim3(DD / 128, MTOT / 128), blk, 0, stream>>>(Obf, wob, out);  // (16, 32)
}